// Round 1
// baseline (608.657 us; speedup 1.0000x reference)
//
#include <hip/hip_runtime.h>

// ---------- constants ----------
#define HID 2048
#define NH 16
#define QLR 1536
#define KVLR 512
#define DN 128
#define DR 64
#define DV 128
#define BB 2
#define SS 2048
#define NTOK (BB*SS)   // 4096
#define QD 3072        // H*(DN+DR)
#define KVD 4096       // H*(DN+DV)
#define CKVD 576       // DR+KVLR

typedef __bf16 bf16x8 __attribute__((ext_vector_type(8)));
typedef float f32x4 __attribute__((ext_vector_type(4)));
typedef unsigned short us4v __attribute__((ext_vector_type(4)));

__device__ __forceinline__ unsigned short f2bf(float f){
  unsigned u = __builtin_bit_cast(unsigned, f);
  return (unsigned short)((u + 0x7fffu + ((u>>16)&1u)) >> 16);
}
__device__ __forceinline__ float bf2f(unsigned short h){
  unsigned u = ((unsigned)h)<<16; return __builtin_bit_cast(float, u);
}

#define GLOAD16(g, l) __builtin_amdgcn_global_load_lds( \
    (const __attribute__((address_space(1))) void*)(const void*)(g), \
    (__attribute__((address_space(3))) void*)(void*)(l), 16, 0, 0)

// ---------- fp32 -> bf16 convert (vectorized) ----------
__global__ void cvt_f32_bf16(const float* __restrict__ in, unsigned short* __restrict__ out, int n4){
  int i = blockIdx.x*256 + threadIdx.x;
  if (i < n4){
    float4 v = ((const float4*)in)[i];
    us4v o = { f2bf(v.x), f2bf(v.y), f2bf(v.z), f2bf(v.w) };
    ((us4v*)out)[i] = o;
  }
}

// ---------- weight transpose + convert: W[K][N] f32 -> WT[Npad][K] bf16 ----------
__global__ void wtrans(const float* __restrict__ W, unsigned short* __restrict__ WT,
                       int K, int N){
  __shared__ float t[32][33];
  int n0 = blockIdx.x*32, k0 = blockIdx.y*32;
  int tx = threadIdx.x & 31, ty = threadIdx.x >> 5;
  #pragma unroll
  for (int i = ty; i < 32; i += 8){
    int k = k0 + i, n = n0 + tx;
    t[i][tx] = (n < N) ? W[(size_t)k*N + n] : 0.f;
  }
  __syncthreads();
  #pragma unroll
  for (int i = ty; i < 32; i += 8){
    int n = n0 + i, k = k0 + tx;
    WT[(size_t)n*K + k] = f2bf(t[tx][i]);
  }
}

// ---------- bf16 GEMM: C[M][N] = A[M][K] @ BT[N][K]^T + bias ----------
// 128x128 tile, BK=32, 4 waves, 16x16x32 MFMA, global_load_lds staging
template<bool OUTF32>
__global__ __launch_bounds__(256) void gemm_bt(
  const unsigned short* __restrict__ A, int lda,
  const unsigned short* __restrict__ BT,
  const float* __restrict__ bias,
  void* __restrict__ Cv, int ldc,
  int N, int K)
{
  __shared__ unsigned short As[128*32];
  __shared__ unsigned short Bs[128*32];
  const int tid = threadIdx.x;
  const int wave = tid>>6, lane = tid&63, lq = lane&15, lg = lane>>4;
  const int tm = blockIdx.y*128, tn = blockIdx.x*128;
  const int wm = (wave>>1)*64, wn = (wave&1)*64;
  f32x4 acc[4][4] = {};
  char* AsB = (char*)As; char* BsB = (char*)Bs;
  const int r0 = tid>>2; const int kb = (tid&3)*8;
  for (int kt = 0; kt < K; kt += 32){
    __syncthreads();
    GLOAD16(A  + (size_t)(tm +      r0)*lda + kt + kb, AsB +        wave*1024);
    GLOAD16(A  + (size_t)(tm + 64 + r0)*lda + kt + kb, AsB + 4096 + wave*1024);
    GLOAD16(BT + (size_t)(tn +      r0)*K   + kt + kb, BsB +        wave*1024);
    GLOAD16(BT + (size_t)(tn + 64 + r0)*K   + kt + kb, BsB + 4096 + wave*1024);
    asm volatile("s_waitcnt vmcnt(0)" ::: "memory");
    __syncthreads();
    bf16x8 af[4], bfr[4];
    #pragma unroll
    for (int i=0;i<4;i++) af[i]  = *(const bf16x8*)(As + (wm+16*i+lq)*32 + lg*8);
    #pragma unroll
    for (int j=0;j<4;j++) bfr[j] = *(const bf16x8*)(Bs + (wn+16*j+lq)*32 + lg*8);
    #pragma unroll
    for (int i=0;i<4;i++)
      #pragma unroll
      for (int j=0;j<4;j++)
        acc[i][j] = __builtin_amdgcn_mfma_f32_16x16x32_bf16(af[i], bfr[j], acc[i][j], 0,0,0);
  }
  #pragma unroll
  for (int i=0;i<4;i++){
    #pragma unroll
    for (int j=0;j<4;j++){
      int col = tn + wn + 16*j + lq;
      if (col < N){
        float bv = bias ? bias[col] : 0.f;
        #pragma unroll
        for (int r=0;r<4;r++){
          int row = tm + wm + 16*i + lg*4 + r;
          float v = acc[i][j][r] + bv;
          if (OUTF32) ((float*)Cv)[(size_t)row*ldc + col] = v;
          else ((unsigned short*)Cv)[(size_t)row*ldc + col] = f2bf(v);
        }
      }
    }
  }
}

// ---------- in-place rmsnorm over bf16 rows ----------
__global__ void rms_inplace(unsigned short* __restrict__ buf, int rowlen, int off, int D){
  __shared__ float red[4];
  int row = blockIdx.x, tid = threadIdx.x;
  unsigned short* x = buf + (size_t)row*rowlen + off;
  float ss = 0.f;
  for (int i = tid; i < D; i += 256){ float v = bf2f(x[i]); ss += v*v; }
  #pragma unroll
  for (int o=32;o;o>>=1) ss += __shfl_xor(ss, o, 64);
  if ((tid&63)==0) red[tid>>6] = ss;
  __syncthreads();
  float tot = red[0]+red[1]+red[2]+red[3];
  float sc = rsqrtf(tot/(float)D + 1e-6f);
  for (int i = tid; i < D; i += 256) x[i] = f2bf(bf2f(x[i])*sc);
}

// ---------- RoPE in-place on q_tmp rope section ----------
__global__ void rope_q_inplace(unsigned short* __restrict__ q){
  int idx = blockIdx.x*256 + threadIdx.x;   // B*S*H*32
  int j = idx & 31;
  int h = (idx >> 5) & 15;
  int t = idx >> 9;            // token
  int s = t & (SS-1);
  unsigned short* base = q + (size_t)t*QD + h*(DN+DR) + DN;
  float xr = bf2f(base[j]), xi = bf2f(base[j+32]);
  float freq = powf(10000.f, -(float)(2*j)/64.f);
  float ang = (float)s * freq;
  float c = cosf(ang), sn = sinf(ang);
  base[j]    = f2bf(xr*c - xi*sn);
  base[j+32] = f2bf(xi*c + xr*sn);
}

// ---------- k_rope: rope(ckv[:, :64]) -> kr[token][64] ----------
__global__ void rope_k(const unsigned short* __restrict__ ckv, unsigned short* __restrict__ kr){
  int idx = blockIdx.x*256 + threadIdx.x;   // B*S*32
  int j = idx & 31;
  int t = idx >> 5;
  int s = t & (SS-1);
  const unsigned short* src = ckv + (size_t)t*CKVD;
  float xr = bf2f(src[j]), xi = bf2f(src[j+32]);
  float freq = powf(10000.f, -(float)(2*j)/64.f);
  float ang = (float)s * freq;
  float c = cosf(ang), sn = sinf(ang);
  kr[(size_t)t*64 + j]      = f2bf(xr*c - xi*sn);
  kr[(size_t)t*64 + j + 32] = f2bf(xi*c + xr*sn);
}

// ---------- V transpose: kv[token][h*256+128+d] -> vT[bh][d][s] ----------
__global__ void transpose_v(const unsigned short* __restrict__ kv, unsigned short* __restrict__ vT){
  __shared__ unsigned short t[32][33];
  int bh = blockIdx.z, b = bh>>4, h = bh&15;
  int s0 = blockIdx.x*32, d0 = blockIdx.y*32;
  int tx = threadIdx.x & 31, ty = threadIdx.x >> 5;
  #pragma unroll
  for (int i = ty; i < 32; i += 8)
    t[i][tx] = kv[((size_t)(b*SS + s0+i))*KVD + h*(DN+DV) + DN + d0 + tx];
  __syncthreads();
  #pragma unroll
  for (int i = ty; i < 32; i += 8)
    vT[((size_t)(bh*DV + d0+i))*SS + s0 + tx] = t[tx][i];
}

// ---------- causal flash attention ----------
// grid (qt=S/64, bh=32). 4 waves x 16 q-rows. Swapped QK^T (S^T=K.Q^T) so the
// softmax column (q) is lane-local (lane&15); P goes through per-wave LDS tile.
__global__ __launch_bounds__(256) void attn_kernel(
  const unsigned short* __restrict__ q,   // [NTOK][3072] rope-applied
  const unsigned short* __restrict__ kv,  // [NTOK][4096]
  const unsigned short* __restrict__ kr,  // [NTOK][64] roped
  const unsigned short* __restrict__ vT,  // [32][128][S]
  unsigned short* __restrict__ attn)      // [NTOK][2048]
{
  __shared__ unsigned short Ksn[32*128];
  __shared__ unsigned short Ksr[32*64];
  __shared__ unsigned short Vs[128*32];
  __shared__ unsigned short Ps[4*512];
  const int tid = threadIdx.x, wave = tid>>6, lane = tid&63, lq = lane&15, lg = lane>>4;
  const int qt = blockIdx.x, bh = blockIdx.y;
  const int b = bh>>4, h = bh&15;
  const int q0 = qt*64, qw = q0 + wave*16;
  const int myq = qw + lq;
  bf16x8 qf[6];
  {
    const unsigned short* qrow = q + (size_t)(b*SS + qw + lq)*QD + h*(DN+DR);
    #pragma unroll
    for (int ks=0;ks<6;ks++) qf[ks] = *(const bf16x8*)(qrow + ks*32 + lg*8);
  }
  f32x4 oacc[8] = {};
  float m = -1e30f, lsum = 0.f;
  const float kmul = 1.44269504f * 0.07216878364f; // log2e / sqrt(192)
  const int nkt = 2*qt + 2;
  char* KsnB=(char*)Ksn; char* KsrB=(char*)Ksr; char* VsB=(char*)Vs;
  for (int kt = 0; kt < nkt; kt++){
    __syncthreads();
    {
      int li0 = tid, li1 = 256 + tid;
      GLOAD16(kv + (size_t)(b*SS + kt*32 + (li0>>4))*KVD + h*(DN+DV) + (li0&15)*8, KsnB +        wave*1024);
      GLOAD16(kv + (size_t)(b*SS + kt*32 + (li1>>4))*KVD + h*(DN+DV) + (li1&15)*8, KsnB + 4096 + wave*1024);
      GLOAD16(kr + (size_t)(b*SS + kt*32 + (tid>>3))*64 + (tid&7)*8,               KsrB +        wave*1024);
      GLOAD16(vT + ((size_t)bh*DV + (li0>>2))*SS + kt*32 + (li0&3)*8,              VsB  +        wave*1024);
      GLOAD16(vT + ((size_t)bh*DV + (li1>>2))*SS + kt*32 + (li1&3)*8,              VsB  + 4096 + wave*1024);
    }
    asm volatile("s_waitcnt vmcnt(0)" ::: "memory");
    __syncthreads();
    f32x4 sacc[2] = {};
    #pragma unroll
    for (int jf=0;jf<2;jf++){
      #pragma unroll
      for (int ks=0;ks<4;ks++){
        bf16x8 kf = *(const bf16x8*)(Ksn + (jf*16+lq)*128 + ks*32 + lg*8);
        sacc[jf] = __builtin_amdgcn_mfma_f32_16x16x32_bf16(kf, qf[ks], sacc[jf], 0,0,0);
      }
      #pragma unroll
      for (int ks=0;ks<2;ks++){
        bf16x8 kf = *(const bf16x8*)(Ksr + (jf*16+lq)*64 + ks*32 + lg*8);
        sacc[jf] = __builtin_amdgcn_mfma_f32_16x16x32_bf16(kf, qf[4+ks], sacc[jf], 0,0,0);
      }
    }
    float sv[2][4]; float pmax = -1e30f;
    #pragma unroll
    for (int jf=0;jf<2;jf++)
      #pragma unroll
      for (int r=0;r<4;r++){
        int kpos = kt*32 + jf*16 + lg*4 + r;
        float s = (kpos <= myq) ? sacc[jf][r]*kmul : -1e30f;
        sv[jf][r] = s; pmax = fmaxf(pmax, s);
      }
    pmax = fmaxf(pmax, __shfl_xor(pmax, 16, 64));
    pmax = fmaxf(pmax, __shfl_xor(pmax, 32, 64));
    float mnew = fmaxf(m, pmax);
    float alpha = __builtin_amdgcn_exp2f(m - mnew);
    m = mnew;
    float psum = 0.f;
    #pragma unroll
    for (int jf=0;jf<2;jf++){
      float p[4];
      #pragma unroll
      for (int r=0;r<4;r++){ p[r] = __builtin_amdgcn_exp2f(sv[jf][r] - m); psum += p[r]; }
      us4v pk = { f2bf(p[0]), f2bf(p[1]), f2bf(p[2]), f2bf(p[3]) };
      *(us4v*)(Ps + wave*512 + lq*32 + jf*16 + lg*4) = pk;
    }
    psum += __shfl_xor(psum, 16, 64);
    psum += __shfl_xor(psum, 32, 64);
    lsum = lsum*alpha + psum;
    bf16x8 pf = *(const bf16x8*)(Ps + wave*512 + lq*32 + lg*8);
    #pragma unroll
    for (int df=0;df<8;df++){
      #pragma unroll
      for (int r=0;r<4;r++) oacc[df][r] *= alpha;
      bf16x8 vf = *(const bf16x8*)(Vs + (df*16+lq)*32 + lg*8);
      oacc[df] = __builtin_amdgcn_mfma_f32_16x16x32_bf16(vf, pf, oacc[df], 0,0,0);
    }
  }
  float inv = 1.f / lsum;
  #pragma unroll
  for (int df=0;df<8;df++){
    us4v o = { f2bf(oacc[df][0]*inv), f2bf(oacc[df][1]*inv),
               f2bf(oacc[df][2]*inv), f2bf(oacc[df][3]*inv) };
    *(us4v*)(attn + (size_t)(b*SS + myq)*2048 + h*DV + df*16 + lg*4) = o;
  }
}

// ---------- launch ----------
extern "C" void kernel_launch(void* const* d_in, const int* in_sizes, int n_in,
                              void* d_out, int out_size, void* d_ws, size_t ws_size,
                              hipStream_t stream){
  const float* X    = (const float*)d_in[0];
  const float* Wqd  = (const float*)d_in[2];
  const float* bqd  = (const float*)d_in[3];
  const float* Wqu  = (const float*)d_in[4];
  const float* bqu  = (const float*)d_in[5];
  const float* Wkvd = (const float*)d_in[6];
  const float* bkvd = (const float*)d_in[7];
  const float* Wkvu = (const float*)d_in[8];
  const float* bkvu = (const float*)d_in[9];
  const float* Wo   = (const float*)d_in[10];
  const float* bo   = (const float*)d_in[11];
  float* out = (float*)d_out;

  char* ws = (char*)d_ws;
  // workspace layout (bytes)
  unsigned short* Xb   = (unsigned short*)(ws + 0);          // 4096*2048*2   = 16777216
  unsigned short* Wt   = (unsigned short*)(ws + 16777216);   // max 3072*1536*2 = 9437184
  unsigned short* cq   = (unsigned short*)(ws + 26214400);   // 4096*1536*2  = 12582912
  unsigned short* qtmp = (unsigned short*)(ws + 38797312);   // 4096*3072*2  = 25165824
  unsigned short* ckv  = (unsigned short*)(ws + 63963136);   // 4096*576*2   = 4718592
  unsigned short* kvt  = (unsigned short*)(ws + 68681728);   // 4096*4096*2  = 33554432
  unsigned short* kr   = (unsigned short*)(ws + 102236160);  // 4096*64*2    = 524288
  unsigned short* vT   = (unsigned short*)(ws + 102760448);  // 32*128*2048*2= 16777216
  unsigned short* attn = (unsigned short*)(ws + 119537664);  // 4096*2048*2  = 16777216

  // 1. X -> bf16
  cvt_f32_bf16<<<dim3(NTOK*HID/4/256), 256, 0, stream>>>(X, Xb, NTOK*HID/4);
  // 2. Wq_down^T ; GEMM1 -> cq ; rmsnorm
  wtrans<<<dim3(QLR/32, HID/32), 256, 0, stream>>>(Wqd, Wt, HID, QLR);
  gemm_bt<false><<<dim3(QLR/128, NTOK/128), 256, 0, stream>>>(Xb, HID, Wt, bqd, cq, QLR, QLR, HID);
  rms_inplace<<<dim3(NTOK), 256, 0, stream>>>(cq, QLR, 0, QLR);
  // 3. Wq_up^T ; GEMM2 -> qtmp ; rope q
  wtrans<<<dim3(QD/32, QLR/32), 256, 0, stream>>>(Wqu, Wt, QLR, QD);
  gemm_bt<false><<<dim3(QD/128, NTOK/128), 256, 0, stream>>>(cq, QLR, Wt, bqu, qtmp, QD, QD, QLR);
  rope_q_inplace<<<dim3(NTOK*NH*32/256), 256, 0, stream>>>(qtmp);
  // 4. Wkv_down^T (pad 576->640) ; GEMM3 -> ckv ; rmsnorm(cols 64..575) ; k_rope
  wtrans<<<dim3(640/32, HID/32), 256, 0, stream>>>(Wkvd, Wt, HID, CKVD);
  gemm_bt<false><<<dim3(640/128, NTOK/128), 256, 0, stream>>>(Xb, HID, Wt, bkvd, ckv, CKVD, CKVD, HID);
  rms_inplace<<<dim3(NTOK), 256, 0, stream>>>(ckv, CKVD, DR, KVLR);
  rope_k<<<dim3(NTOK*32/256), 256, 0, stream>>>(ckv, kr);
  // 5. Wkv_up^T ; GEMM4 -> kvt
  wtrans<<<dim3(KVD/32, KVLR/32), 256, 0, stream>>>(Wkvu, Wt, KVLR, KVD);
  gemm_bt<false><<<dim3(KVD/128, NTOK/128), 256, 0, stream>>>(ckv + DR, CKVD, Wt, bkvu, kvt, KVD, KVD, KVLR);
  // 6. V^T
  transpose_v<<<dim3(SS/32, DV/32, 32), 256, 0, stream>>>(kvt, vT);
  // 7. attention
  attn_kernel<<<dim3(SS/64, BB*NH), 256, 0, stream>>>(qtmp, kvt, kr, vT, attn);
  // 8. Wo^T ; GEMM5 -> out (f32)
  wtrans<<<dim3(HID/32, HID/32), 256, 0, stream>>>(Wo, Wt, HID, HID);
  gemm_bt<true><<<dim3(HID/128, NTOK/128), 256, 0, stream>>>(attn, HID, Wt, bo, out, HID, HID, HID);
}

// Round 2
// 454.238 us; speedup vs baseline: 1.3400x; 1.3400x over previous
//
#include <hip/hip_runtime.h>

// ---------- constants ----------
#define HID 2048
#define NH 16
#define QLR 1536
#define KVLR 512
#define DN 128
#define DR 64
#define DV 128
#define BB 2
#define SS 2048
#define NTOK (BB*SS)   // 4096
#define QD 3072        // H*(DN+DR)
#define KVD 4096       // H*(DN+DV)
#define CKVD 576       // DR+KVLR
#define NQT (SS/64)    // 32 q-tiles

typedef __bf16 bf16x8 __attribute__((ext_vector_type(8)));
typedef float f32x4 __attribute__((ext_vector_type(4)));
typedef unsigned short us4v __attribute__((ext_vector_type(4)));

__device__ __forceinline__ unsigned short f2bf(float f){
  unsigned u = __builtin_bit_cast(unsigned, f);
  return (unsigned short)((u + 0x7fffu + ((u>>16)&1u)) >> 16);
}
__device__ __forceinline__ float bf2f(unsigned short h){
  unsigned u = ((unsigned)h)<<16; return __builtin_bit_cast(float, u);
}

#define GLOAD16(g, l) __builtin_amdgcn_global_load_lds( \
    (const __attribute__((address_space(1))) void*)(const void*)(g), \
    (__attribute__((address_space(3))) void*)(void*)(l), 16, 0, 0)

// ---------- fp32 -> bf16 convert (vectorized) ----------
__global__ void cvt_f32_bf16(const float* __restrict__ in, unsigned short* __restrict__ out, int n4){
  int i = blockIdx.x*256 + threadIdx.x;
  if (i < n4){
    float4 v = ((const float4*)in)[i];
    us4v o = { f2bf(v.x), f2bf(v.y), f2bf(v.z), f2bf(v.w) };
    ((us4v*)out)[i] = o;
  }
}

// ---------- weight transpose + convert: W[K][N] f32 -> WT[Npad][K] bf16 ----------
__global__ void wtrans(const float* __restrict__ W, unsigned short* __restrict__ WT,
                       int K, int N){
  __shared__ float t[32][33];
  int n0 = blockIdx.x*32, k0 = blockIdx.y*32;
  int tx = threadIdx.x & 31, ty = threadIdx.x >> 5;
  #pragma unroll
  for (int i = ty; i < 32; i += 8){
    int k = k0 + i, n = n0 + tx;
    t[i][tx] = (n < N) ? W[(size_t)k*N + n] : 0.f;
  }
  __syncthreads();
  #pragma unroll
  for (int i = ty; i < 32; i += 8){
    int n = n0 + i, k = k0 + tx;
    WT[(size_t)n*K + k] = f2bf(t[tx][i]);
  }
}

// ---------- bf16 GEMM: C[M][N] = A[M][K] @ BT[N][K]^T + bias ----------
// 128x128 tile, BK=32, 4 waves, 16x16x32 MFMA, global_load_lds staging
template<bool OUTF32>
__global__ __launch_bounds__(256) void gemm_bt(
  const unsigned short* __restrict__ A, int lda,
  const unsigned short* __restrict__ BT,
  const float* __restrict__ bias,
  void* __restrict__ Cv, int ldc,
  int N, int K)
{
  __shared__ unsigned short As[128*32];
  __shared__ unsigned short Bs[128*32];
  const int tid = threadIdx.x;
  const int wave = tid>>6, lane = tid&63, lq = lane&15, lg = lane>>4;
  const int tm = blockIdx.y*128, tn = blockIdx.x*128;
  const int wm = (wave>>1)*64, wn = (wave&1)*64;
  f32x4 acc[4][4] = {};
  char* AsB = (char*)As; char* BsB = (char*)Bs;
  const int r0 = tid>>2; const int kb = (tid&3)*8;
  for (int kt = 0; kt < K; kt += 32){
    __syncthreads();
    GLOAD16(A  + (size_t)(tm +      r0)*lda + kt + kb, AsB +        wave*1024);
    GLOAD16(A  + (size_t)(tm + 64 + r0)*lda + kt + kb, AsB + 4096 + wave*1024);
    GLOAD16(BT + (size_t)(tn +      r0)*K   + kt + kb, BsB +        wave*1024);
    GLOAD16(BT + (size_t)(tn + 64 + r0)*K   + kt + kb, BsB + 4096 + wave*1024);
    asm volatile("s_waitcnt vmcnt(0)" ::: "memory");
    __syncthreads();
    bf16x8 af[4], bfr[4];
    #pragma unroll
    for (int i=0;i<4;i++) af[i]  = *(const bf16x8*)(As + (wm+16*i+lq)*32 + lg*8);
    #pragma unroll
    for (int j=0;j<4;j++) bfr[j] = *(const bf16x8*)(Bs + (wn+16*j+lq)*32 + lg*8);
    #pragma unroll
    for (int i=0;i<4;i++)
      #pragma unroll
      for (int j=0;j<4;j++)
        acc[i][j] = __builtin_amdgcn_mfma_f32_16x16x32_bf16(af[i], bfr[j], acc[i][j], 0,0,0);
  }
  #pragma unroll
  for (int i=0;i<4;i++){
    #pragma unroll
    for (int j=0;j<4;j++){
      int col = tn + wn + 16*j + lq;
      if (col < N){
        float bv = bias ? bias[col] : 0.f;
        #pragma unroll
        for (int r=0;r<4;r++){
          int row = tm + wm + 16*i + lg*4 + r;
          float v = acc[i][j][r] + bv;
          if (OUTF32) ((float*)Cv)[(size_t)row*ldc + col] = v;
          else ((unsigned short*)Cv)[(size_t)row*ldc + col] = f2bf(v);
        }
      }
    }
  }
}

// ---------- in-place rmsnorm over bf16 rows ----------
__global__ void rms_inplace(unsigned short* __restrict__ buf, int rowlen, int off, int D){
  __shared__ float red[4];
  int row = blockIdx.x, tid = threadIdx.x;
  unsigned short* x = buf + (size_t)row*rowlen + off;
  float ss = 0.f;
  for (int i = tid; i < D; i += 256){ float v = bf2f(x[i]); ss += v*v; }
  #pragma unroll
  for (int o=32;o;o>>=1) ss += __shfl_xor(ss, o, 64);
  if ((tid&63)==0) red[tid>>6] = ss;
  __syncthreads();
  float tot = red[0]+red[1]+red[2]+red[3];
  float sc = rsqrtf(tot/(float)D + 1e-6f);
  for (int i = tid; i < D; i += 256) x[i] = f2bf(bf2f(x[i])*sc);
}

// ---------- RoPE in-place on q_tmp rope section ----------
__global__ void rope_q_inplace(unsigned short* __restrict__ q){
  int idx = blockIdx.x*256 + threadIdx.x;   // B*S*H*32
  int j = idx & 31;
  int h = (idx >> 5) & 15;
  int t = idx >> 9;            // token
  int s = t & (SS-1);
  unsigned short* base = q + (size_t)t*QD + h*(DN+DR) + DN;
  float xr = bf2f(base[j]), xi = bf2f(base[j+32]);
  float freq = powf(10000.f, -(float)(2*j)/64.f);
  float ang = (float)s * freq;
  float c = cosf(ang), sn = sinf(ang);
  base[j]    = f2bf(xr*c - xi*sn);
  base[j+32] = f2bf(xi*c + xr*sn);
}

// ---------- k_rope: rope(ckv[:, :64]) -> kr[token][64] ----------
__global__ void rope_k(const unsigned short* __restrict__ ckv, unsigned short* __restrict__ kr){
  int idx = blockIdx.x*256 + threadIdx.x;   // B*S*32
  int j = idx & 31;
  int t = idx >> 5;
  int s = t & (SS-1);
  const unsigned short* src = ckv + (size_t)t*CKVD;
  float xr = bf2f(src[j]), xi = bf2f(src[j+32]);
  float freq = powf(10000.f, -(float)(2*j)/64.f);
  float ang = (float)s * freq;
  float c = cosf(ang), sn = sinf(ang);
  kr[(size_t)t*64 + j]      = f2bf(xr*c - xi*sn);
  kr[(size_t)t*64 + j + 32] = f2bf(xi*c + xr*sn);
}

// ---------- V transpose: kv[token][h*256+128+d] -> vT[bh][d][s] ----------
__global__ void transpose_v(const unsigned short* __restrict__ kv, unsigned short* __restrict__ vT){
  __shared__ unsigned short t[32][33];
  int bh = blockIdx.z, b = bh>>4, h = bh&15;
  int s0 = blockIdx.x*32, d0 = blockIdx.y*32;
  int tx = threadIdx.x & 31, ty = threadIdx.x >> 5;
  #pragma unroll
  for (int i = ty; i < 32; i += 8)
    t[i][tx] = kv[((size_t)(b*SS + s0+i))*KVD + h*(DN+DV) + DN + d0 + tx];
  __syncthreads();
  #pragma unroll
  for (int i = ty; i < 32; i += 8)
    vT[((size_t)(bh*DV + d0+i))*SS + s0 + tx] = t[tx][i];
}

// ---------- causal flash attention ----------
// grid (pair=NQT/2, bh=32). 4 waves x 16 q-rows, QBLK=64, KVBLK=32.
// Swapped QK^T (S^T=K.Q^T), q lane-local. Per block: q-tile p then NQT-1-p
// (causal balance: every block = 66 k-steps exactly).
// K tiles XOR-swizzled (chunk ^= row&7) via pre-swizzled global source
// (linear global_load_lds dest) + swizzled ds_read — kills the 16-way
// bank conflict of 256B/128B rows. Double-buffered 2-phase prefetch:
// issue next tile's loads before computing current; vmcnt(0)+barrier once
// per k-step waits on loads issued one full compute phase earlier.
__global__ __launch_bounds__(256) void attn_kernel(
  const unsigned short* __restrict__ q,   // [NTOK][3072] rope-applied
  const unsigned short* __restrict__ kv,  // [NTOK][4096]
  const unsigned short* __restrict__ kr,  // [NTOK][64] roped
  const unsigned short* __restrict__ vT,  // [32][128][S]
  unsigned short* __restrict__ attn)      // [NTOK][2048]
{
  __shared__ unsigned short Ksn[2][32*128];
  __shared__ unsigned short Ksr[2][32*64];
  __shared__ unsigned short Vs [2][128*32];
  __shared__ unsigned short Ps [4*512];
  const int tid = threadIdx.x, wave = tid>>6, lane = tid&63, lq = lane&15, lg = lane>>4;
  const int pairid = blockIdx.x, bh = blockIdx.y;
  const int b = bh>>4, h = bh&15;
  const float kmul = 1.44269504f * 0.07216878364f; // log2e / sqrt(192)

#define STAGE_ATTN(bufi, kt_) do {                                            \
    int li0 = tid, li1 = 256 + tid;                                           \
    { int r_ = li0>>4, c_ = (li0&15) ^ (r_&7);                                \
      GLOAD16(kv + (size_t)(b*SS + (kt_)*32 + r_)*KVD + h*(DN+DV) + c_*8,     \
              (char*)Ksn[bufi] + wave*1024); }                                \
    { int r_ = li1>>4, c_ = (li1&15) ^ (r_&7);                                \
      GLOAD16(kv + (size_t)(b*SS + (kt_)*32 + r_)*KVD + h*(DN+DV) + c_*8,     \
              (char*)Ksn[bufi] + 4096 + wave*1024); }                         \
    { int r_ = tid>>3, c_ = (tid&7) ^ (r_&7);                                 \
      GLOAD16(kr + (size_t)(b*SS + (kt_)*32 + r_)*64 + c_*8,                  \
              (char*)Ksr[bufi] + wave*1024); }                                \
    GLOAD16(vT + ((size_t)bh*DV + (li0>>2))*SS + (kt_)*32 + (li0&3)*8,        \
            (char*)Vs[bufi] + wave*1024);                                     \
    GLOAD16(vT + ((size_t)bh*DV + (li1>>2))*SS + (kt_)*32 + (li1&3)*8,        \
            (char*)Vs[bufi] + 4096 + wave*1024);                              \
  } while(0)

  for (int half = 0; half < 2; half++){
    const int qt = half ? (NQT-1 - pairid) : pairid;
    const int qw = qt*64 + wave*16;
    const int myq = qw + lq;
    bf16x8 qf[6];
    {
      const unsigned short* qrow = q + (size_t)(b*SS + qw + lq)*QD + h*(DN+DR);
      #pragma unroll
      for (int ks=0;ks<6;ks++) qf[ks] = *(const bf16x8*)(qrow + ks*32 + lg*8);
    }
    f32x4 oacc[8] = {};
    float m = -1e30f, lsum = 0.f;
    const int nkt = 2*qt + 2;

    STAGE_ATTN(0, 0);
    asm volatile("s_waitcnt vmcnt(0)" ::: "memory");
    __syncthreads();
    int cur = 0;
    for (int kt = 0; kt < nkt; kt++){
      if (kt+1 < nkt) STAGE_ATTN(cur^1, kt+1);
      // ---- QK^T (swizzled K reads) ----
      f32x4 sacc[2] = {};
      __builtin_amdgcn_s_setprio(1);
      #pragma unroll
      for (int jf=0;jf<2;jf++){
        const int rowb = jf*16 + lq;
        #pragma unroll
        for (int ks=0;ks<4;ks++){
          bf16x8 kf = *(const bf16x8*)((char*)Ksn[cur] + rowb*256 + ((((ks*4+lg)^(lq&7)))<<4));
          sacc[jf] = __builtin_amdgcn_mfma_f32_16x16x32_bf16(kf, qf[ks], sacc[jf], 0,0,0);
        }
        #pragma unroll
        for (int ks=0;ks<2;ks++){
          bf16x8 kf = *(const bf16x8*)((char*)Ksr[cur] + rowb*128 + ((((ks*4+lg)^(lq&7)))<<4));
          sacc[jf] = __builtin_amdgcn_mfma_f32_16x16x32_bf16(kf, qf[4+ks], sacc[jf], 0,0,0);
        }
      }
      __builtin_amdgcn_s_setprio(0);
      // ---- online softmax (q is lane-local: col=lq) ----
      float sv[2][4]; float pmax = -1e30f;
      #pragma unroll
      for (int jf=0;jf<2;jf++)
        #pragma unroll
        for (int r=0;r<4;r++){
          int kpos = kt*32 + jf*16 + lg*4 + r;
          float s = (kpos <= myq) ? sacc[jf][r]*kmul : -1e30f;
          sv[jf][r] = s; pmax = fmaxf(pmax, s);
        }
      pmax = fmaxf(pmax, __shfl_xor(pmax, 16, 64));
      pmax = fmaxf(pmax, __shfl_xor(pmax, 32, 64));
      float mnew = fmaxf(m, pmax);
      float alpha = __builtin_amdgcn_exp2f(m - mnew);
      m = mnew;
      float psum = 0.f;
      #pragma unroll
      for (int jf=0;jf<2;jf++){
        float p[4];
        #pragma unroll
        for (int r=0;r<4;r++){ p[r] = __builtin_amdgcn_exp2f(sv[jf][r] - m); psum += p[r]; }
        us4v pk = { f2bf(p[0]), f2bf(p[1]), f2bf(p[2]), f2bf(p[3]) };
        *(us4v*)(Ps + wave*512 + lq*32 + jf*16 + lg*4) = pk;
      }
      psum += __shfl_xor(psum, 16, 64);
      psum += __shfl_xor(psum, 32, 64);
      lsum = lsum*alpha + psum;
      bf16x8 pf = *(const bf16x8*)(Ps + wave*512 + lq*32 + lg*8);
      // ---- PV ----
      __builtin_amdgcn_s_setprio(1);
      #pragma unroll
      for (int df=0;df<8;df++){
        #pragma unroll
        for (int r=0;r<4;r++) oacc[df][r] *= alpha;
        bf16x8 vf = *(const bf16x8*)(Vs[cur] + (df*16+lq)*32 + lg*8);
        oacc[df] = __builtin_amdgcn_mfma_f32_16x16x32_bf16(vf, pf, oacc[df], 0,0,0);
      }
      __builtin_amdgcn_s_setprio(0);
      asm volatile("s_waitcnt vmcnt(0)" ::: "memory");
      __syncthreads();
      cur ^= 1;
    }
    float inv = 1.f / lsum;
    #pragma unroll
    for (int df=0;df<8;df++){
      us4v o = { f2bf(oacc[df][0]*inv), f2bf(oacc[df][1]*inv),
                 f2bf(oacc[df][2]*inv), f2bf(oacc[df][3]*inv) };
      *(us4v*)(attn + (size_t)(b*SS + myq)*2048 + h*DV + df*16 + lg*4) = o;
    }
  }
#undef STAGE_ATTN
}

// ---------- launch ----------
extern "C" void kernel_launch(void* const* d_in, const int* in_sizes, int n_in,
                              void* d_out, int out_size, void* d_ws, size_t ws_size,
                              hipStream_t stream){
  const float* X    = (const float*)d_in[0];
  const float* Wqd  = (const float*)d_in[2];
  const float* bqd  = (const float*)d_in[3];
  const float* Wqu  = (const float*)d_in[4];
  const float* bqu  = (const float*)d_in[5];
  const float* Wkvd = (const float*)d_in[6];
  const float* bkvd = (const float*)d_in[7];
  const float* Wkvu = (const float*)d_in[8];
  const float* bkvu = (const float*)d_in[9];
  const float* Wo   = (const float*)d_in[10];
  const float* bo   = (const float*)d_in[11];
  float* out = (float*)d_out;

  char* ws = (char*)d_ws;
  // workspace layout (bytes)
  unsigned short* Xb   = (unsigned short*)(ws + 0);          // 4096*2048*2   = 16777216
  unsigned short* Wt   = (unsigned short*)(ws + 16777216);   // max 3072*1536*2 = 9437184
  unsigned short* cq   = (unsigned short*)(ws + 26214400);   // 4096*1536*2  = 12582912
  unsigned short* qtmp = (unsigned short*)(ws + 38797312);   // 4096*3072*2  = 25165824
  unsigned short* ckv  = (unsigned short*)(ws + 63963136);   // 4096*576*2   = 4718592
  unsigned short* kvt  = (unsigned short*)(ws + 68681728);   // 4096*4096*2  = 33554432
  unsigned short* kr   = (unsigned short*)(ws + 102236160);  // 4096*64*2    = 524288
  unsigned short* vT   = (unsigned short*)(ws + 102760448);  // 32*128*2048*2= 16777216
  unsigned short* attn = (unsigned short*)(ws + 119537664);  // 4096*2048*2  = 16777216

  // 1. X -> bf16
  cvt_f32_bf16<<<dim3(NTOK*HID/4/256), 256, 0, stream>>>(X, Xb, NTOK*HID/4);
  // 2. Wq_down^T ; GEMM1 -> cq ; rmsnorm
  wtrans<<<dim3(QLR/32, HID/32), 256, 0, stream>>>(Wqd, Wt, HID, QLR);
  gemm_bt<false><<<dim3(QLR/128, NTOK/128), 256, 0, stream>>>(Xb, HID, Wt, bqd, cq, QLR, QLR, HID);
  rms_inplace<<<dim3(NTOK), 256, 0, stream>>>(cq, QLR, 0, QLR);
  // 3. Wq_up^T ; GEMM2 -> qtmp ; rope q
  wtrans<<<dim3(QD/32, QLR/32), 256, 0, stream>>>(Wqu, Wt, QLR, QD);
  gemm_bt<false><<<dim3(QD/128, NTOK/128), 256, 0, stream>>>(cq, QLR, Wt, bqu, qtmp, QD, QD, QLR);
  rope_q_inplace<<<dim3(NTOK*NH*32/256), 256, 0, stream>>>(qtmp);
  // 4. Wkv_down^T (pad 576->640) ; GEMM3 -> ckv ; rmsnorm(cols 64..575) ; k_rope
  wtrans<<<dim3(640/32, HID/32), 256, 0, stream>>>(Wkvd, Wt, HID, CKVD);
  gemm_bt<false><<<dim3(640/128, NTOK/128), 256, 0, stream>>>(Xb, HID, Wt, bkvd, ckv, CKVD, CKVD, HID);
  rms_inplace<<<dim3(NTOK), 256, 0, stream>>>(ckv, CKVD, DR, KVLR);
  rope_k<<<dim3(NTOK*32/256), 256, 0, stream>>>(ckv, kr);
  // 5. Wkv_up^T ; GEMM4 -> kvt
  wtrans<<<dim3(KVD/32, KVLR/32), 256, 0, stream>>>(Wkvu, Wt, KVLR, KVD);
  gemm_bt<false><<<dim3(KVD/128, NTOK/128), 256, 0, stream>>>(ckv + DR, CKVD, Wt, bkvu, kvt, KVD, KVD, KVLR);
  // 6. V^T
  transpose_v<<<dim3(SS/32, DV/32, 32), 256, 0, stream>>>(kvt, vT);
  // 7. attention (causal-paired blocks)
  attn_kernel<<<dim3(NQT/2, BB*NH), 256, 0, stream>>>(qtmp, kvt, kr, vT, attn);
  // 8. Wo^T ; GEMM5 -> out (f32)
  wtrans<<<dim3(HID/32, HID/32), 256, 0, stream>>>(Wo, Wt, HID, HID);
  gemm_bt<true><<<dim3(HID/128, NTOK/128), 256, 0, stream>>>(attn, HID, Wt, bo, out, HID, HID, HID);
}

// Round 3
// 374.782 us; speedup vs baseline: 1.6240x; 1.2120x over previous
//
#include <hip/hip_runtime.h>

// ---------- constants ----------
#define HID 2048
#define NH 16
#define QLR 1536
#define KVLR 512
#define DN 128
#define DR 64
#define DV 128
#define BB 2
#define SS 2048
#define NTOK (BB*SS)   // 4096
#define QD 3072        // H*(DN+DR)
#define KVD 4096       // H*(DN+DV)
#define CKVD 576       // DR+KVLR
#define NQT (SS/64)    // 32 q-tiles

typedef __bf16 bf16x8 __attribute__((ext_vector_type(8)));
typedef float f32x4 __attribute__((ext_vector_type(4)));
typedef unsigned short us4v __attribute__((ext_vector_type(4)));

__device__ __forceinline__ unsigned short f2bf(float f){
  unsigned u = __builtin_bit_cast(unsigned, f);
  return (unsigned short)((u + 0x7fffu + ((u>>16)&1u)) >> 16);
}
__device__ __forceinline__ float bf2f(unsigned short h){
  unsigned u = ((unsigned)h)<<16; return __builtin_bit_cast(float, u);
}
__device__ __forceinline__ unsigned cvt_pk_bf16(float a, float b){
  unsigned r;
  asm("v_cvt_pk_bf16_f32 %0, %1, %2" : "=v"(r) : "v"(a), "v"(b));
  return r;
}

#define GLOAD16(g, l) __builtin_amdgcn_global_load_lds( \
    (const __attribute__((address_space(1))) void*)(const void*)(g), \
    (__attribute__((address_space(3))) void*)(void*)(l), 16, 0, 0)

// ---------- fp32 -> bf16 convert (vectorized) ----------
__global__ void cvt_f32_bf16(const float* __restrict__ in, unsigned short* __restrict__ out, int n4){
  int i = blockIdx.x*256 + threadIdx.x;
  if (i < n4){
    float4 v = ((const float4*)in)[i];
    us4v o = { f2bf(v.x), f2bf(v.y), f2bf(v.z), f2bf(v.w) };
    ((us4v*)out)[i] = o;
  }
}

// ---------- weight transpose + convert: W[K][N] f32 -> WT[Npad][K] bf16 ----------
__global__ void wtrans(const float* __restrict__ W, unsigned short* __restrict__ WT,
                       int K, int N){
  __shared__ float t[32][33];
  int n0 = blockIdx.x*32, k0 = blockIdx.y*32;
  int tx = threadIdx.x & 31, ty = threadIdx.x >> 5;
  #pragma unroll
  for (int i = ty; i < 32; i += 8){
    int k = k0 + i, n = n0 + tx;
    t[i][tx] = (n < N) ? W[(size_t)k*N + n] : 0.f;
  }
  __syncthreads();
  #pragma unroll
  for (int i = ty; i < 32; i += 8){
    int n = n0 + i, k = k0 + tx;
    WT[(size_t)n*K + k] = f2bf(t[tx][i]);
  }
}

// ---------- bf16 GEMM core: C[M][N] = A[M][K] @ BT[N][K]^T + bias ----------
// 128x128 tile, BK=64, 4 waves, 16x16x32 MFMA, global_load_lds staging.
// LDS rows are 128B -> XOR-chunk swizzle (chunk c ^= row&7) applied on the
// global source (linear LDS dest, rule 21) and on the ds_read address.
template<bool OUTF32>
__device__ __forceinline__ void gemm_core(
  unsigned short* As, unsigned short* Bs,
  const unsigned short* __restrict__ A, int lda,
  const unsigned short* __restrict__ BT,
  const float* __restrict__ bias,
  void* __restrict__ Cv, int ldc,
  int N, int K, int bx, int by)
{
  const int tid = threadIdx.x;
  const int wave = tid>>6, lane = tid&63, lq = lane&15, lg = lane>>4;
  const int tm = by*128, tn = bx*128;
  const int wm = (wave>>1)*64, wn = (wave&1)*64;
  f32x4 acc[4][4] = {};
  char* AsB = (char*)As; char* BsB = (char*)Bs;
  const int r8 = tid>>3;                 // row within 32-row group
  const int sc = ((tid&7) ^ (r8&7))*8;   // swizzled source col (shorts)
  for (int kt = 0; kt < K; kt += 64){
    __syncthreads();
    #pragma unroll
    for (int rd=0; rd<4; rd++){
      GLOAD16(A  + (size_t)(tm + rd*32 + r8)*lda + kt + sc, AsB + rd*4096 + wave*1024);
      GLOAD16(BT + (size_t)(tn + rd*32 + r8)*K   + kt + sc, BsB + rd*4096 + wave*1024);
    }
    asm volatile("s_waitcnt vmcnt(0)" ::: "memory");
    __syncthreads();
    #pragma unroll
    for (int h=0; h<2; h++){
      bf16x8 af[4], bfr[4];
      #pragma unroll
      for (int i=0;i<4;i++) af[i]  = *(const bf16x8*)(AsB + (wm+16*i+lq)*128 + ((((h*4+lg)^(lq&7)))<<4));
      #pragma unroll
      for (int j=0;j<4;j++) bfr[j] = *(const bf16x8*)(BsB + (wn+16*j+lq)*128 + ((((h*4+lg)^(lq&7)))<<4));
      #pragma unroll
      for (int i=0;i<4;i++)
        #pragma unroll
        for (int j=0;j<4;j++)
          acc[i][j] = __builtin_amdgcn_mfma_f32_16x16x32_bf16(af[i], bfr[j], acc[i][j], 0,0,0);
    }
  }
  #pragma unroll
  for (int i=0;i<4;i++){
    #pragma unroll
    for (int j=0;j<4;j++){
      int col = tn + wn + 16*j + lq;
      if (col < N){
        float bv = bias ? bias[col] : 0.f;
        #pragma unroll
        for (int r=0;r<4;r++){
          int row = tm + wm + 16*i + lg*4 + r;
          float v = acc[i][j][r] + bv;
          if (OUTF32) ((float*)Cv)[(size_t)row*ldc + col] = v;
          else ((unsigned short*)Cv)[(size_t)row*ldc + col] = f2bf(v);
        }
      }
    }
  }
}

template<bool OUTF32>
__global__ __launch_bounds__(256) void gemm_bt(
  const unsigned short* __restrict__ A, int lda,
  const unsigned short* __restrict__ BT,
  const float* __restrict__ bias,
  void* __restrict__ Cv, int ldc, int N, int K)
{
  __shared__ unsigned short As[128*64];
  __shared__ unsigned short Bs[128*64];
  gemm_core<OUTF32>(As, Bs, A, lda, BT, bias, Cv, ldc, N, K, blockIdx.x, blockIdx.y);
}

// two independent GEMMs in one dispatch (better CU fill, fewer tails)
__global__ __launch_bounds__(256) void gemm_bt_dual(
  const unsigned short* __restrict__ A0, int lda0, const unsigned short* __restrict__ BT0,
  const float* __restrict__ b0, void* __restrict__ C0, int ldc0, int N0, int K0,
  const unsigned short* __restrict__ A1, int lda1, const unsigned short* __restrict__ BT1,
  const float* __restrict__ b1, void* __restrict__ C1, int ldc1, int N1, int K1,
  int split)
{
  __shared__ unsigned short As[128*64];
  __shared__ unsigned short Bs[128*64];
  if ((int)blockIdx.x < split)
    gemm_core<false>(As, Bs, A0, lda0, BT0, b0, C0, ldc0, N0, K0, blockIdx.x, blockIdx.y);
  else
    gemm_core<false>(As, Bs, A1, lda1, BT1, b1, C1, ldc1, N1, K1, blockIdx.x - split, blockIdx.y);
}

// ---------- in-place rmsnorm over bf16 rows ----------
__global__ void rms_inplace(unsigned short* __restrict__ buf, int rowlen, int off, int D){
  __shared__ float red[4];
  int row = blockIdx.x, tid = threadIdx.x;
  unsigned short* x = buf + (size_t)row*rowlen + off;
  float ss = 0.f;
  for (int i = tid; i < D; i += 256){ float v = bf2f(x[i]); ss += v*v; }
  #pragma unroll
  for (int o=32;o;o>>=1) ss += __shfl_xor(ss, o, 64);
  if ((tid&63)==0) red[tid>>6] = ss;
  __syncthreads();
  float tot = red[0]+red[1]+red[2]+red[3];
  float sc = rsqrtf(tot/(float)D + 1e-6f);
  for (int i = tid; i < D; i += 256) x[i] = f2bf(bf2f(x[i])*sc);
}

// ---------- RoPE in-place on q_tmp rope section ----------
__global__ void rope_q_inplace(unsigned short* __restrict__ q){
  int idx = blockIdx.x*256 + threadIdx.x;   // B*S*H*32
  int j = idx & 31;
  int h = (idx >> 5) & 15;
  int t = idx >> 9;            // token
  int s = t & (SS-1);
  unsigned short* base = q + (size_t)t*QD + h*(DN+DR) + DN;
  float xr = bf2f(base[j]), xi = bf2f(base[j+32]);
  float freq = powf(10000.f, -(float)(2*j)/64.f);
  float ang = (float)s * freq;
  float c = cosf(ang), sn = sinf(ang);
  base[j]    = f2bf(xr*c - xi*sn);
  base[j+32] = f2bf(xi*c + xr*sn);
}

// ---------- k_rope: rope(ckv[:, :64]) -> kr[token][64] ----------
__global__ void rope_k(const unsigned short* __restrict__ ckv, unsigned short* __restrict__ kr){
  int idx = blockIdx.x*256 + threadIdx.x;   // B*S*32
  int j = idx & 31;
  int t = idx >> 5;
  int s = t & (SS-1);
  const unsigned short* src = ckv + (size_t)t*CKVD;
  float xr = bf2f(src[j]), xi = bf2f(src[j+32]);
  float freq = powf(10000.f, -(float)(2*j)/64.f);
  float ang = (float)s * freq;
  float c = cosf(ang), sn = sinf(ang);
  kr[(size_t)t*64 + j]      = f2bf(xr*c - xi*sn);
  kr[(size_t)t*64 + j + 32] = f2bf(xi*c + xr*sn);
}

// ---------- V transpose: kv[token][h*256+128+d] -> vT[bh][d][s] ----------
__global__ void transpose_v(const unsigned short* __restrict__ kv, unsigned short* __restrict__ vT){
  __shared__ unsigned short t[32][33];
  int bh = blockIdx.z, b = bh>>4, h = bh&15;
  int s0 = blockIdx.x*32, d0 = blockIdx.y*32;
  int tx = threadIdx.x & 31, ty = threadIdx.x >> 5;
  #pragma unroll
  for (int i = ty; i < 32; i += 8)
    t[i][tx] = kv[((size_t)(b*SS + s0+i))*KVD + h*(DN+DV) + DN + d0 + tx];
  __syncthreads();
  #pragma unroll
  for (int i = ty; i < 32; i += 8)
    vT[((size_t)(bh*DV + d0+i))*SS + s0 + tx] = t[tx][i];
}

// ---------- causal flash attention ----------
// grid (pair=NQT/2, bh=32). 4 waves x 16 q-rows, QBLK=64, KVBLK=32.
// Swapped QK^T (S^T=K.Q^T), q lane-local. Causal pairing: q-tile p then
// NQT-1-p (every block = 66 k-steps). 3-buffer / 2-deep prefetch with
// COUNTED vmcnt(5) + raw s_barrier (never drain to 0 in steady state —
// __syncthreads would force a vmcnt(0) drain). K tiles XOR-swizzled.
// Softmax: wave-uniform unmasked fast path; defer-max (THR=8) skips the
// O-rescale on most tiles; P packed via v_cvt_pk_bf16_f32.
__global__ __launch_bounds__(256) void attn_kernel(
  const unsigned short* __restrict__ q,   // [NTOK][3072] rope-applied
  const unsigned short* __restrict__ kv,  // [NTOK][4096]
  const unsigned short* __restrict__ kr,  // [NTOK][64] roped
  const unsigned short* __restrict__ vT,  // [32][128][S]
  unsigned short* __restrict__ attn)      // [NTOK][2048]
{
  __shared__ unsigned short Ksn[3][32*128];
  __shared__ unsigned short Ksr[3][32*64];
  __shared__ unsigned short Vs [3][128*32];
  __shared__ unsigned short Ps [4*512];
  const int tid = threadIdx.x, wave = tid>>6, lane = tid&63, lq = lane&15, lg = lane>>4;
  const int pairid = blockIdx.x, bh = blockIdx.y;
  const int b = bh>>4, h = bh&15;
  const float kmul = 1.44269504f * 0.07216878364f; // log2e / sqrt(192)

#define STAGE_ATTN(bufi, kt_) do {                                            \
    int li0 = tid, li1 = 256 + tid;                                           \
    { int r_ = li0>>4, c_ = (li0&15) ^ (r_&7);                                \
      GLOAD16(kv + (size_t)(b*SS + (kt_)*32 + r_)*KVD + h*(DN+DV) + c_*8,     \
              (char*)Ksn[bufi] + wave*1024); }                                \
    { int r_ = li1>>4, c_ = (li1&15) ^ (r_&7);                                \
      GLOAD16(kv + (size_t)(b*SS + (kt_)*32 + r_)*KVD + h*(DN+DV) + c_*8,     \
              (char*)Ksn[bufi] + 4096 + wave*1024); }                         \
    { int r_ = tid>>3, c_ = (tid&7) ^ (r_&7);                                 \
      GLOAD16(kr + (size_t)(b*SS + (kt_)*32 + r_)*64 + c_*8,                  \
              (char*)Ksr[bufi] + wave*1024); }                                \
    GLOAD16(vT + ((size_t)bh*DV + (li0>>2))*SS + (kt_)*32 + (li0&3)*8,        \
            (char*)Vs[bufi] + wave*1024);                                     \
    GLOAD16(vT + ((size_t)bh*DV + (li1>>2))*SS + (kt_)*32 + (li1&3)*8,        \
            (char*)Vs[bufi] + 4096 + wave*1024);                              \
  } while(0)

  for (int half = 0; half < 2; half++){
    const int qt = half ? (NQT-1 - pairid) : pairid;
    const int qw = qt*64 + wave*16;
    const int myq = qw + lq;
    bf16x8 qf[6];
    {
      const unsigned short* qrow = q + (size_t)(b*SS + qw + lq)*QD + h*(DN+DR);
      #pragma unroll
      for (int ks=0;ks<6;ks++) qf[ks] = *(const bf16x8*)(qrow + ks*32 + lg*8);
    }
    f32x4 oacc[8] = {};
    float m = -1e30f, lsum = 0.f;
    const int nkt = 2*qt + 2;   // >= 2 always

    STAGE_ATTN(0, 0);
    STAGE_ATTN(1, 1);
    asm volatile("s_waitcnt vmcnt(5)" ::: "memory");
    __builtin_amdgcn_s_barrier();
    for (int kt = 0; kt < nkt; kt++){
      const int cur = kt%3;
      const bool more = (kt+2 < nkt);
      if (more){ int nb = cur+2; if (nb>=3) nb-=3; STAGE_ATTN(nb, kt+2); }
      // ---- QK^T (swizzled K reads) ----
      f32x4 sacc[2] = {};
      __builtin_amdgcn_s_setprio(1);
      #pragma unroll
      for (int jf=0;jf<2;jf++){
        const int rowb = jf*16 + lq;
        #pragma unroll
        for (int ks=0;ks<4;ks++){
          bf16x8 kf = *(const bf16x8*)((char*)Ksn[cur] + rowb*256 + ((((ks*4+lg)^(lq&7)))<<4));
          sacc[jf] = __builtin_amdgcn_mfma_f32_16x16x32_bf16(kf, qf[ks], sacc[jf], 0,0,0);
        }
        #pragma unroll
        for (int ks=0;ks<2;ks++){
          bf16x8 kf = *(const bf16x8*)((char*)Ksr[cur] + rowb*128 + ((((ks*4+lg)^(lq&7)))<<4));
          sacc[jf] = __builtin_amdgcn_mfma_f32_16x16x32_bf16(kf, qf[4+ks], sacc[jf], 0,0,0);
        }
      }
      __builtin_amdgcn_s_setprio(0);
      // ---- online softmax (q lane-local: col=lq) ----
      float sv[2][4]; float pmax = -1e30f;
      if (kt*32 + 31 <= qw){          // wave-uniform: fully visible tile
        #pragma unroll
        for (int jf=0;jf<2;jf++)
          #pragma unroll
          for (int r=0;r<4;r++){ float s = sacc[jf][r]*kmul; sv[jf][r]=s; pmax=fmaxf(pmax,s); }
      } else {
        #pragma unroll
        for (int jf=0;jf<2;jf++)
          #pragma unroll
          for (int r=0;r<4;r++){
            int kpos = kt*32 + jf*16 + lg*4 + r;
            float s = (kpos <= myq) ? sacc[jf][r]*kmul : -1e30f;
            sv[jf][r]=s; pmax=fmaxf(pmax,s);
          }
      }
      pmax = fmaxf(pmax, __shfl_xor(pmax, 16, 64));
      pmax = fmaxf(pmax, __shfl_xor(pmax, 32, 64));
      if (!__all(pmax <= m + 8.f)){   // defer-max: rescale only on real growth
        float mnew = fmaxf(m, pmax);
        float alpha = __builtin_amdgcn_exp2f(m - mnew);
        m = mnew;
        lsum *= alpha;
        #pragma unroll
        for (int df=0;df<8;df++)
          #pragma unroll
          for (int r=0;r<4;r++) oacc[df][r] *= alpha;
      }
      float psum = 0.f;
      #pragma unroll
      for (int jf=0;jf<2;jf++){
        float p0 = __builtin_amdgcn_exp2f(sv[jf][0] - m);
        float p1 = __builtin_amdgcn_exp2f(sv[jf][1] - m);
        float p2 = __builtin_amdgcn_exp2f(sv[jf][2] - m);
        float p3 = __builtin_amdgcn_exp2f(sv[jf][3] - m);
        psum += (p0+p1)+(p2+p3);
        uint2 pk = { cvt_pk_bf16(p0,p1), cvt_pk_bf16(p2,p3) };
        *(uint2*)((char*)Ps + wave*1024 + lq*64 + jf*32 + lg*8) = pk;
      }
      psum += __shfl_xor(psum, 16, 64);
      psum += __shfl_xor(psum, 32, 64);
      lsum += psum;
      bf16x8 pf = *(const bf16x8*)((char*)Ps + wave*1024 + lq*64 + lg*16);
      // ---- PV ----
      __builtin_amdgcn_s_setprio(1);
      #pragma unroll
      for (int df=0;df<8;df++){
        bf16x8 vf = *(const bf16x8*)(Vs[cur] + (df*16+lq)*32 + lg*8);
        oacc[df] = __builtin_amdgcn_mfma_f32_16x16x32_bf16(vf, pf, oacc[df], 0,0,0);
      }
      __builtin_amdgcn_s_setprio(0);
      if (more) asm volatile("s_waitcnt vmcnt(5)" ::: "memory");
      else      asm volatile("s_waitcnt vmcnt(0)" ::: "memory");
      __builtin_amdgcn_s_barrier();
    }
    float inv = 1.f / lsum;
    #pragma unroll
    for (int df=0;df<8;df++){
      uint2 o = { cvt_pk_bf16(oacc[df][0]*inv, oacc[df][1]*inv),
                  cvt_pk_bf16(oacc[df][2]*inv, oacc[df][3]*inv) };
      *(uint2*)(attn + (size_t)(b*SS + myq)*2048 + h*DV + df*16 + lg*4) = o;
    }
  }
#undef STAGE_ATTN
}

// ---------- launch ----------
extern "C" void kernel_launch(void* const* d_in, const int* in_sizes, int n_in,
                              void* d_out, int out_size, void* d_ws, size_t ws_size,
                              hipStream_t stream){
  const float* X    = (const float*)d_in[0];
  const float* Wqd  = (const float*)d_in[2];
  const float* bqd  = (const float*)d_in[3];
  const float* Wqu  = (const float*)d_in[4];
  const float* bqu  = (const float*)d_in[5];
  const float* Wkvd = (const float*)d_in[6];
  const float* bkvd = (const float*)d_in[7];
  const float* Wkvu = (const float*)d_in[8];
  const float* bkvu = (const float*)d_in[9];
  const float* Wo   = (const float*)d_in[10];
  const float* bo   = (const float*)d_in[11];
  float* out = (float*)d_out;

  char* ws = (char*)d_ws;
  // workspace layout (bytes); attn output overlays Xb (dead after G1G3)
  unsigned short* Xb    = (unsigned short*)(ws + 0);          // 16,777,216
  unsigned short* attnb = (unsigned short*)(ws + 0);
  char*           arena = ws + 16777216;                      // 14,680,064 (weight arena)
  unsigned short* Wt1 = (unsigned short*)(arena);             // 1536x2048x2 = 6,291,456
  unsigned short* Wt3 = (unsigned short*)(arena + 6291456);   // 640x2048x2  = 2,621,440
  unsigned short* Wt2 = (unsigned short*)(arena);             // 3072x1536x2 = 9,437,184
  unsigned short* Wt4 = (unsigned short*)(arena + 9437184);   // 4096x512x2  = 4,194,304
  unsigned short* Wt5 = (unsigned short*)(arena);             // 2048x2048x2 = 8,388,608
  unsigned short* cq   = (unsigned short*)(ws + 31457280);    // 12,582,912
  unsigned short* qtmp = (unsigned short*)(ws + 44040192);    // 25,165,824
  unsigned short* ckv  = (unsigned short*)(ws + 69206016);    //  4,718,592
  unsigned short* kvt  = (unsigned short*)(ws + 73924608);    // 33,554,432
  unsigned short* kr   = (unsigned short*)(ws + 107479040);   //    524,288
  unsigned short* vT   = (unsigned short*)(ws + 108003328);   // 16,777,216  (end 124,780,544)

  // 1. X -> bf16
  cvt_f32_bf16<<<dim3(NTOK*HID/4/256), 256, 0, stream>>>(X, Xb, NTOK*HID/4);
  // 2. W transposes for down-projections, fused G1+G3
  wtrans<<<dim3(QLR/32, HID/32), 256, 0, stream>>>(Wqd, Wt1, HID, QLR);
  wtrans<<<dim3(640/32, HID/32), 256, 0, stream>>>(Wkvd, Wt3, HID, CKVD);
  gemm_bt_dual<<<dim3(QLR/128 + 640/128, NTOK/128), 256, 0, stream>>>(
      Xb, HID, Wt1, bqd, cq, QLR, QLR, HID,
      Xb, HID, Wt3, bkvd, ckv, CKVD, CKVD, HID, QLR/128);
  // 3. norms + k rope
  rms_inplace<<<dim3(NTOK), 256, 0, stream>>>(cq, QLR, 0, QLR);
  rms_inplace<<<dim3(NTOK), 256, 0, stream>>>(ckv, CKVD, DR, KVLR);
  rope_k<<<dim3(NTOK*32/256), 256, 0, stream>>>(ckv, kr);
  // 4. W transposes for up-projections, fused G2+G4
  wtrans<<<dim3(QD/32, QLR/32), 256, 0, stream>>>(Wqu, Wt2, QLR, QD);
  wtrans<<<dim3(KVD/32, KVLR/32), 256, 0, stream>>>(Wkvu, Wt4, KVLR, KVD);
  gemm_bt_dual<<<dim3(QD/128 + KVD/128, NTOK/128), 256, 0, stream>>>(
      cq, QLR, Wt2, bqu, qtmp, QD, QD, QLR,
      ckv + DR, CKVD, Wt4, bkvu, kvt, KVD, KVD, KVLR, QD/128);
  // 5. q rope, V^T
  rope_q_inplace<<<dim3(NTOK*NH*32/256), 256, 0, stream>>>(qtmp);
  transpose_v<<<dim3(SS/32, DV/32, 32), 256, 0, stream>>>(kvt, vT);
  // 6. attention (causal-paired blocks)
  attn_kernel<<<dim3(NQT/2, BB*NH), 256, 0, stream>>>(qtmp, kvt, kr, vT, attnb);
  // 7. Wo^T ; GEMM5 -> out (f32)
  wtrans<<<dim3(HID/32, HID/32), 256, 0, stream>>>(Wo, Wt5, HID, HID);
  gemm_bt<true><<<dim3(HID/128, NTOK/128), 256, 0, stream>>>(attnb, HID, Wt5, bo, out, HID, HID, HID);
}

// Round 4
// 363.833 us; speedup vs baseline: 1.6729x; 1.0301x over previous
//
#include <hip/hip_runtime.h>

// ---------- constants ----------
#define HID 2048
#define NH 16
#define QLR 1536
#define KVLR 512
#define DN 128
#define DR 64
#define DV 128
#define BB 2
#define SS 2048
#define NTOK (BB*SS)   // 4096
#define QD 3072        // H*(DN+DR)
#define KVD 4096       // H*(DN+DV)
#define CKVD 576       // DR+KVLR
#define NQT (SS/64)    // 32 q-tiles

typedef __bf16 bf16x8 __attribute__((ext_vector_type(8)));
typedef float f32x4 __attribute__((ext_vector_type(4)));
typedef unsigned short us4v __attribute__((ext_vector_type(4)));

__device__ __forceinline__ unsigned short f2bf(float f){
  unsigned u = __builtin_bit_cast(unsigned, f);
  return (unsigned short)((u + 0x7fffu + ((u>>16)&1u)) >> 16);
}
__device__ __forceinline__ float bf2f(unsigned short h){
  unsigned u = ((unsigned)h)<<16; return __builtin_bit_cast(float, u);
}
__device__ __forceinline__ unsigned cvt_pk_bf16(float a, float b){
  unsigned r;
  asm("v_cvt_pk_bf16_f32 %0, %1, %2" : "=v"(r) : "v"(a), "v"(b));
  return r;
}

#define GLOAD16(g, l) __builtin_amdgcn_global_load_lds( \
    (const __attribute__((address_space(1))) void*)(const void*)(g), \
    (__attribute__((address_space(3))) void*)(void*)(l), 16, 0, 0)

// ---------- fp32 -> bf16 convert (vectorized) ----------
__global__ void cvt_f32_bf16(const float* __restrict__ in, unsigned short* __restrict__ out, int n4){
  int i = blockIdx.x*256 + threadIdx.x;
  if (i < n4){
    float4 v = ((const float4*)in)[i];
    us4v o = { f2bf(v.x), f2bf(v.y), f2bf(v.z), f2bf(v.w) };
    ((us4v*)out)[i] = o;
  }
}

// ---------- weight transpose + convert: W[K][N] f32 -> WT[Npad][K] bf16 ----------
__global__ void wtrans(const float* __restrict__ W, unsigned short* __restrict__ WT,
                       int K, int N){
  __shared__ float t[32][33];
  int n0 = blockIdx.x*32, k0 = blockIdx.y*32;
  int tx = threadIdx.x & 31, ty = threadIdx.x >> 5;
  #pragma unroll
  for (int i = ty; i < 32; i += 8){
    int k = k0 + i, n = n0 + tx;
    t[i][tx] = (n < N) ? W[(size_t)k*N + n] : 0.f;
  }
  __syncthreads();
  #pragma unroll
  for (int i = ty; i < 32; i += 8){
    int n = n0 + i, k = k0 + tx;
    WT[(size_t)n*K + k] = f2bf(t[tx][i]);
  }
}

// ---------- bf16 GEMM core: C[M][N] = A[M][K] @ BT[N][K]^T + bias ----------
// 128x128 tile, BK=64, 4 waves, 16x16x32 MFMA, global_load_lds staging.
// LDS rows are 128B -> XOR-chunk swizzle (chunk c ^= row&7) applied on the
// global source (linear LDS dest, rule 21) and on the ds_read address.
template<bool OUTF32>
__device__ __forceinline__ void gemm_core(
  unsigned short* As, unsigned short* Bs,
  const unsigned short* __restrict__ A, int lda,
  const unsigned short* __restrict__ BT,
  const float* __restrict__ bias,
  void* __restrict__ Cv, int ldc,
  int N, int K, int bx, int by)
{
  const int tid = threadIdx.x;
  const int wave = tid>>6, lane = tid&63, lq = lane&15, lg = lane>>4;
  const int tm = by*128, tn = bx*128;
  const int wm = (wave>>1)*64, wn = (wave&1)*64;
  f32x4 acc[4][4] = {};
  char* AsB = (char*)As; char* BsB = (char*)Bs;
  const int r8 = tid>>3;                 // row within 32-row group
  const int sc = ((tid&7) ^ (r8&7))*8;   // swizzled source col (shorts)
  for (int kt = 0; kt < K; kt += 64){
    __syncthreads();
    #pragma unroll
    for (int rd=0; rd<4; rd++){
      GLOAD16(A  + (size_t)(tm + rd*32 + r8)*lda + kt + sc, AsB + rd*4096 + wave*1024);
      GLOAD16(BT + (size_t)(tn + rd*32 + r8)*K   + kt + sc, BsB + rd*4096 + wave*1024);
    }
    asm volatile("s_waitcnt vmcnt(0)" ::: "memory");
    __syncthreads();
    #pragma unroll
    for (int h=0; h<2; h++){
      bf16x8 af[4], bfr[4];
      #pragma unroll
      for (int i=0;i<4;i++) af[i]  = *(const bf16x8*)(AsB + (wm+16*i+lq)*128 + ((((h*4+lg)^(lq&7)))<<4));
      #pragma unroll
      for (int j=0;j<4;j++) bfr[j] = *(const bf16x8*)(BsB + (wn+16*j+lq)*128 + ((((h*4+lg)^(lq&7)))<<4));
      #pragma unroll
      for (int i=0;i<4;i++)
        #pragma unroll
        for (int j=0;j<4;j++)
          acc[i][j] = __builtin_amdgcn_mfma_f32_16x16x32_bf16(af[i], bfr[j], acc[i][j], 0,0,0);
    }
  }
  #pragma unroll
  for (int i=0;i<4;i++){
    #pragma unroll
    for (int j=0;j<4;j++){
      int col = tn + wn + 16*j + lq;
      if (col < N){
        float bv = bias ? bias[col] : 0.f;
        #pragma unroll
        for (int r=0;r<4;r++){
          int row = tm + wm + 16*i + lg*4 + r;
          float v = acc[i][j][r] + bv;
          if (OUTF32) ((float*)Cv)[(size_t)row*ldc + col] = v;
          else ((unsigned short*)Cv)[(size_t)row*ldc + col] = f2bf(v);
        }
      }
    }
  }
}

template<bool OUTF32>
__global__ __launch_bounds__(256) void gemm_bt(
  const unsigned short* __restrict__ A, int lda,
  const unsigned short* __restrict__ BT,
  const float* __restrict__ bias,
  void* __restrict__ Cv, int ldc, int N, int K)
{
  __shared__ unsigned short As[128*64];
  __shared__ unsigned short Bs[128*64];
  gemm_core<OUTF32>(As, Bs, A, lda, BT, bias, Cv, ldc, N, K, blockIdx.x, blockIdx.y);
}

// two independent GEMMs in one dispatch (better CU fill, fewer tails)
__global__ __launch_bounds__(256) void gemm_bt_dual(
  const unsigned short* __restrict__ A0, int lda0, const unsigned short* __restrict__ BT0,
  const float* __restrict__ b0, void* __restrict__ C0, int ldc0, int N0, int K0,
  const unsigned short* __restrict__ A1, int lda1, const unsigned short* __restrict__ BT1,
  const float* __restrict__ b1, void* __restrict__ C1, int ldc1, int N1, int K1,
  int split)
{
  __shared__ unsigned short As[128*64];
  __shared__ unsigned short Bs[128*64];
  if ((int)blockIdx.x < split)
    gemm_core<false>(As, Bs, A0, lda0, BT0, b0, C0, ldc0, N0, K0, blockIdx.x, blockIdx.y);
  else
    gemm_core<false>(As, Bs, A1, lda1, BT1, b1, C1, ldc1, N1, K1, blockIdx.x - split, blockIdx.y);
}

// ---------- in-place rmsnorm over bf16 rows ----------
__global__ void rms_inplace(unsigned short* __restrict__ buf, int rowlen, int off, int D){
  __shared__ float red[4];
  int row = blockIdx.x, tid = threadIdx.x;
  unsigned short* x = buf + (size_t)row*rowlen + off;
  float ss = 0.f;
  for (int i = tid; i < D; i += 256){ float v = bf2f(x[i]); ss += v*v; }
  #pragma unroll
  for (int o=32;o;o>>=1) ss += __shfl_xor(ss, o, 64);
  if ((tid&63)==0) red[tid>>6] = ss;
  __syncthreads();
  float tot = red[0]+red[1]+red[2]+red[3];
  float sc = rsqrtf(tot/(float)D + 1e-6f);
  for (int i = tid; i < D; i += 256) x[i] = f2bf(bf2f(x[i])*sc);
}

// ---------- RoPE in-place on q_tmp rope section ----------
__global__ void rope_q_inplace(unsigned short* __restrict__ q){
  int idx = blockIdx.x*256 + threadIdx.x;   // B*S*H*32
  int j = idx & 31;
  int h = (idx >> 5) & 15;
  int t = idx >> 9;            // token
  int s = t & (SS-1);
  unsigned short* base = q + (size_t)t*QD + h*(DN+DR) + DN;
  float xr = bf2f(base[j]), xi = bf2f(base[j+32]);
  float freq = powf(10000.f, -(float)(2*j)/64.f);
  float ang = (float)s * freq;
  float c = cosf(ang), sn = sinf(ang);
  base[j]    = f2bf(xr*c - xi*sn);
  base[j+32] = f2bf(xi*c + xr*sn);
}

// ---------- k_rope: rope(ckv[:, :64]) -> kr[token][64] ----------
__global__ void rope_k(const unsigned short* __restrict__ ckv, unsigned short* __restrict__ kr){
  int idx = blockIdx.x*256 + threadIdx.x;   // B*S*32
  int j = idx & 31;
  int t = idx >> 5;
  int s = t & (SS-1);
  const unsigned short* src = ckv + (size_t)t*CKVD;
  float xr = bf2f(src[j]), xi = bf2f(src[j+32]);
  float freq = powf(10000.f, -(float)(2*j)/64.f);
  float ang = (float)s * freq;
  float c = cosf(ang), sn = sinf(ang);
  kr[(size_t)t*64 + j]      = f2bf(xr*c - xi*sn);
  kr[(size_t)t*64 + j + 32] = f2bf(xi*c + xr*sn);
}

// ---------- V transpose: kv[token][h*256+128+d] -> vT[bh][d][s] ----------
__global__ void transpose_v(const unsigned short* __restrict__ kv, unsigned short* __restrict__ vT){
  __shared__ unsigned short t[32][33];
  int bh = blockIdx.z, b = bh>>4, h = bh&15;
  int s0 = blockIdx.x*32, d0 = blockIdx.y*32;
  int tx = threadIdx.x & 31, ty = threadIdx.x >> 5;
  #pragma unroll
  for (int i = ty; i < 32; i += 8)
    t[i][tx] = kv[((size_t)(b*SS + s0+i))*KVD + h*(DN+DV) + DN + d0 + tx];
  __syncthreads();
  #pragma unroll
  for (int i = ty; i < 32; i += 8)
    vT[((size_t)(bh*DV + d0+i))*SS + s0 + tx] = t[tx][i];
}

// ---------- causal flash attention ----------
// 1-D grid of 512 blocks, XCD-swizzled decode: all 16 pair-blocks of a
// given bh share lin%8 == bh%8 -> same XCD -> K/V stream fetched from HBM
// once per XCD instead of 8x (round-3 profile: 265 MB fetch vs 58 MB
// unique = the whole attn cost). 4 waves x 16 q-rows, QBLK=64, KVBLK=32.
// Swapped QK^T, causal pairing (qt=p then NQT-1-p: 66 k-steps/block).
// 3-buffer 2-deep prefetch, counted vmcnt(5) + raw s_barrier. K tiles
// XOR-swizzled. Defer-max softmax; cvt_pk bf16 packs. Staging addresses
// hoisted into running per-thread pointers.
__global__ __launch_bounds__(256) void attn_kernel(
  const unsigned short* __restrict__ q,   // [NTOK][3072] rope-applied
  const unsigned short* __restrict__ kv,  // [NTOK][4096]
  const unsigned short* __restrict__ kr,  // [NTOK][64] roped
  const unsigned short* __restrict__ vT,  // [32][128][S]
  unsigned short* __restrict__ attn)      // [NTOK][2048]
{
  __shared__ unsigned short Ksn[3][32*128];
  __shared__ unsigned short Ksr[3][32*64];
  __shared__ unsigned short Vs [3][128*32];
  __shared__ unsigned short Ps [4*512];
  const int tid = threadIdx.x, wave = tid>>6, lane = tid&63, lq = lane&15, lg = lane>>4;
  const int lin = blockIdx.x;
  const int bh = (lin&7) + 8*((lin>>3)&3);
  const int pairid = lin >> 5;
  const int b = bh>>4, h = bh&15;
  const float kmul = 1.44269504f * 0.07216878364f; // log2e / sqrt(192)

  // per-thread staging bases (advance per k-step)
  const int rK = tid>>4, cK = (tid&15) ^ ((tid>>4)&7);
  const int rR = tid>>3, cR = (tid&7) ^ ((tid>>3)&7);
  const unsigned short* gKn0_base = kv + (size_t)(b*SS + rK)*KVD + h*(DN+DV) + cK*8;
  const unsigned short* gKn1_base = gKn0_base + (size_t)16*KVD;
  const unsigned short* gKr_base  = kr + (size_t)(b*SS + rR)*64 + cR*8;
  const unsigned short* gV0_base  = vT + ((size_t)bh*DV + (tid>>2))*SS + (tid&3)*8;
  const unsigned short* gV1_base  = gV0_base + (size_t)64*SS;

#define STAGE_ATTN(bufi) do {                                                 \
    GLOAD16(pKn0, (char*)Ksn[bufi] +        wave*1024);                       \
    GLOAD16(pKn1, (char*)Ksn[bufi] + 4096 + wave*1024);                       \
    GLOAD16(pKr,  (char*)Ksr[bufi] +        wave*1024);                       \
    GLOAD16(pV0,  (char*)Vs[bufi]  +        wave*1024);                       \
    GLOAD16(pV1,  (char*)Vs[bufi]  + 4096 + wave*1024);                       \
    pKn0 += 32*KVD; pKn1 += 32*KVD; pKr += 32*64; pV0 += 32; pV1 += 32;       \
  } while(0)

  for (int half = 0; half < 2; half++){
    const int qt = half ? (NQT-1 - pairid) : pairid;
    const int qw = qt*64 + wave*16;
    const int myq = qw + lq;
    bf16x8 qf[6];
    {
      const unsigned short* qrow = q + (size_t)(b*SS + qw + lq)*QD + h*(DN+DR);
      #pragma unroll
      for (int ks=0;ks<6;ks++) qf[ks] = *(const bf16x8*)(qrow + ks*32 + lg*8);
    }
    f32x4 oacc[8] = {};
    float m = -1e30f, lsum = 0.f;
    const int nkt = 2*qt + 2;   // >= 2 always

    const unsigned short* pKn0 = gKn0_base;
    const unsigned short* pKn1 = gKn1_base;
    const unsigned short* pKr  = gKr_base;
    const unsigned short* pV0  = gV0_base;
    const unsigned short* pV1  = gV1_base;

    STAGE_ATTN(0);
    STAGE_ATTN(1);
    asm volatile("s_waitcnt vmcnt(5)" ::: "memory");
    __builtin_amdgcn_s_barrier();
    int cur = 0;
    for (int kt = 0; kt < nkt; kt++){
      const bool more = (kt+2 < nkt);
      if (more){ int nb = cur>=1 ? cur-1 : cur+2; STAGE_ATTN(nb); }
      // ---- QK^T (swizzled K reads) ----
      f32x4 sacc[2] = {};
      __builtin_amdgcn_s_setprio(1);
      #pragma unroll
      for (int jf=0;jf<2;jf++){
        const int rowb = jf*16 + lq;
        #pragma unroll
        for (int ks=0;ks<4;ks++){
          bf16x8 kf = *(const bf16x8*)((char*)Ksn[cur] + rowb*256 + ((((ks*4+lg)^(lq&7)))<<4));
          sacc[jf] = __builtin_amdgcn_mfma_f32_16x16x32_bf16(kf, qf[ks], sacc[jf], 0,0,0);
        }
        #pragma unroll
        for (int ks=0;ks<2;ks++){
          bf16x8 kf = *(const bf16x8*)((char*)Ksr[cur] + rowb*128 + ((((ks*4+lg)^(lq&7)))<<4));
          sacc[jf] = __builtin_amdgcn_mfma_f32_16x16x32_bf16(kf, qf[4+ks], sacc[jf], 0,0,0);
        }
      }
      __builtin_amdgcn_s_setprio(0);
      // ---- online softmax (q lane-local: col=lq) ----
      float sv[2][4]; float pmax = -1e30f;
      if (kt*32 + 31 <= qw){          // wave-uniform: fully visible tile
        #pragma unroll
        for (int jf=0;jf<2;jf++)
          #pragma unroll
          for (int r=0;r<4;r++){ float s = sacc[jf][r]*kmul; sv[jf][r]=s; pmax=fmaxf(pmax,s); }
      } else {
        #pragma unroll
        for (int jf=0;jf<2;jf++)
          #pragma unroll
          for (int r=0;r<4;r++){
            int kpos = kt*32 + jf*16 + lg*4 + r;
            float s = (kpos <= myq) ? sacc[jf][r]*kmul : -1e30f;
            sv[jf][r]=s; pmax=fmaxf(pmax,s);
          }
      }
      pmax = fmaxf(pmax, __shfl_xor(pmax, 16, 64));
      pmax = fmaxf(pmax, __shfl_xor(pmax, 32, 64));
      if (!__all(pmax <= m + 8.f)){   // defer-max: rescale only on real growth
        float mnew = fmaxf(m, pmax);
        float alpha = __builtin_amdgcn_exp2f(m - mnew);
        m = mnew;
        lsum *= alpha;
        #pragma unroll
        for (int df=0;df<8;df++)
          #pragma unroll
          for (int r=0;r<4;r++) oacc[df][r] *= alpha;
      }
      float psum = 0.f;
      #pragma unroll
      for (int jf=0;jf<2;jf++){
        float p0 = __builtin_amdgcn_exp2f(sv[jf][0] - m);
        float p1 = __builtin_amdgcn_exp2f(sv[jf][1] - m);
        float p2 = __builtin_amdgcn_exp2f(sv[jf][2] - m);
        float p3 = __builtin_amdgcn_exp2f(sv[jf][3] - m);
        psum += (p0+p1)+(p2+p3);
        uint2 pk = { cvt_pk_bf16(p0,p1), cvt_pk_bf16(p2,p3) };
        *(uint2*)((char*)Ps + wave*1024 + lq*64 + jf*32 + lg*8) = pk;
      }
      psum += __shfl_xor(psum, 16, 64);
      psum += __shfl_xor(psum, 32, 64);
      lsum += psum;
      bf16x8 pf = *(const bf16x8*)((char*)Ps + wave*1024 + lq*64 + lg*16);
      // ---- PV ----
      __builtin_amdgcn_s_setprio(1);
      #pragma unroll
      for (int df=0;df<8;df++){
        bf16x8 vf = *(const bf16x8*)(Vs[cur] + (df*16+lq)*32 + lg*8);
        oacc[df] = __builtin_amdgcn_mfma_f32_16x16x32_bf16(vf, pf, oacc[df], 0,0,0);
      }
      __builtin_amdgcn_s_setprio(0);
      if (more) asm volatile("s_waitcnt vmcnt(5)" ::: "memory");
      else      asm volatile("s_waitcnt vmcnt(0)" ::: "memory");
      __builtin_amdgcn_s_barrier();
      cur = cur==2 ? 0 : cur+1;
    }
    float inv = 1.f / lsum;
    #pragma unroll
    for (int df=0;df<8;df++){
      uint2 o = { cvt_pk_bf16(oacc[df][0]*inv, oacc[df][1]*inv),
                  cvt_pk_bf16(oacc[df][2]*inv, oacc[df][3]*inv) };
      *(uint2*)(attn + (size_t)(b*SS + myq)*2048 + h*DV + df*16 + lg*4) = o;
    }
  }
#undef STAGE_ATTN
}

// ---------- launch ----------
extern "C" void kernel_launch(void* const* d_in, const int* in_sizes, int n_in,
                              void* d_out, int out_size, void* d_ws, size_t ws_size,
                              hipStream_t stream){
  const float* X    = (const float*)d_in[0];
  const float* Wqd  = (const float*)d_in[2];
  const float* bqd  = (const float*)d_in[3];
  const float* Wqu  = (const float*)d_in[4];
  const float* bqu  = (const float*)d_in[5];
  const float* Wkvd = (const float*)d_in[6];
  const float* bkvd = (const float*)d_in[7];
  const float* Wkvu = (const float*)d_in[8];
  const float* bkvu = (const float*)d_in[9];
  const float* Wo   = (const float*)d_in[10];
  const float* bo   = (const float*)d_in[11];
  float* out = (float*)d_out;

  char* ws = (char*)d_ws;
  // workspace layout (bytes); attn output overlays Xb (dead after G1G3)
  unsigned short* Xb    = (unsigned short*)(ws + 0);          // 16,777,216
  unsigned short* attnb = (unsigned short*)(ws + 0);
  char*           arena = ws + 16777216;                      // 14,680,064 (weight arena)
  unsigned short* Wt1 = (unsigned short*)(arena);             // 1536x2048x2 = 6,291,456
  unsigned short* Wt3 = (unsigned short*)(arena + 6291456);   // 640x2048x2  = 2,621,440
  unsigned short* Wt2 = (unsigned short*)(arena);             // 3072x1536x2 = 9,437,184
  unsigned short* Wt4 = (unsigned short*)(arena + 9437184);   // 4096x512x2  = 4,194,304
  unsigned short* Wt5 = (unsigned short*)(arena);             // 2048x2048x2 = 8,388,608
  unsigned short* cq   = (unsigned short*)(ws + 31457280);    // 12,582,912
  unsigned short* qtmp = (unsigned short*)(ws + 44040192);    // 25,165,824
  unsigned short* ckv  = (unsigned short*)(ws + 69206016);    //  4,718,592
  unsigned short* kvt  = (unsigned short*)(ws + 73924608);    // 33,554,432
  unsigned short* kr   = (unsigned short*)(ws + 107479040);   //    524,288
  unsigned short* vT   = (unsigned short*)(ws + 108003328);   // 16,777,216  (end 124,780,544)

  // 1. X -> bf16
  cvt_f32_bf16<<<dim3(NTOK*HID/4/256), 256, 0, stream>>>(X, Xb, NTOK*HID/4);
  // 2. W transposes for down-projections, fused G1+G3
  wtrans<<<dim3(QLR/32, HID/32), 256, 0, stream>>>(Wqd, Wt1, HID, QLR);
  wtrans<<<dim3(640/32, HID/32), 256, 0, stream>>>(Wkvd, Wt3, HID, CKVD);
  gemm_bt_dual<<<dim3(QLR/128 + 640/128, NTOK/128), 256, 0, stream>>>(
      Xb, HID, Wt1, bqd, cq, QLR, QLR, HID,
      Xb, HID, Wt3, bkvd, ckv, CKVD, CKVD, HID, QLR/128);
  // 3. norms + k rope
  rms_inplace<<<dim3(NTOK), 256, 0, stream>>>(cq, QLR, 0, QLR);
  rms_inplace<<<dim3(NTOK), 256, 0, stream>>>(ckv, CKVD, DR, KVLR);
  rope_k<<<dim3(NTOK*32/256), 256, 0, stream>>>(ckv, kr);
  // 4. W transposes for up-projections, fused G2+G4
  wtrans<<<dim3(QD/32, QLR/32), 256, 0, stream>>>(Wqu, Wt2, QLR, QD);
  wtrans<<<dim3(KVD/32, KVLR/32), 256, 0, stream>>>(Wkvu, Wt4, KVLR, KVD);
  gemm_bt_dual<<<dim3(QD/128 + KVD/128, NTOK/128), 256, 0, stream>>>(
      cq, QLR, Wt2, bqu, qtmp, QD, QD, QLR,
      ckv + DR, CKVD, Wt4, bkvu, kvt, KVD, KVD, KVLR, QD/128);
  // 5. q rope, V^T
  rope_q_inplace<<<dim3(NTOK*NH*32/256), 256, 0, stream>>>(qtmp);
  transpose_v<<<dim3(SS/32, DV/32, 32), 256, 0, stream>>>(kvt, vT);
  // 6. attention (XCD-swizzled 1-D grid, causal-paired blocks)
  attn_kernel<<<dim3(NQT/2 * BB*NH), 256, 0, stream>>>(qtmp, kvt, kr, vT, attnb);
  // 7. Wo^T ; GEMM5 -> out (f32)
  wtrans<<<dim3(HID/32, HID/32), 256, 0, stream>>>(Wo, Wt5, HID, HID);
  gemm_bt<true><<<dim3(HID/128, NTOK/128), 256, 0, stream>>>(attnb, HID, Wt5, bo, out, HID, HID, HID);
}

// Round 5
// 359.969 us; speedup vs baseline: 1.6909x; 1.0107x over previous
//
#include <hip/hip_runtime.h>

// ---------- constants ----------
#define HID 2048
#define NH 16
#define QLR 1536
#define KVLR 512
#define DN 128
#define DR 64
#define DV 128
#define BB 2
#define SS 2048
#define NTOK (BB*SS)   // 4096
#define QD 3072        // H*(DN+DR)
#define KVD 4096       // H*(DN+DV)
#define CKVD 576       // DR+KVLR
#define NQT (SS/64)    // 32 q-tiles

typedef __bf16 bf16x8 __attribute__((ext_vector_type(8)));
typedef float f32x4 __attribute__((ext_vector_type(4)));
typedef unsigned short us4v __attribute__((ext_vector_type(4)));

__device__ __forceinline__ unsigned short f2bf(float f){
  unsigned u = __builtin_bit_cast(unsigned, f);
  return (unsigned short)((u + 0x7fffu + ((u>>16)&1u)) >> 16);
}
__device__ __forceinline__ float bf2f(unsigned short h){
  unsigned u = ((unsigned)h)<<16; return __builtin_bit_cast(float, u);
}
__device__ __forceinline__ unsigned cvt_pk_bf16(float a, float b){
  unsigned r;
  asm("v_cvt_pk_bf16_f32 %0, %1, %2" : "=v"(r) : "v"(a), "v"(b));
  return r;
}

#define GLOAD16(g, l) __builtin_amdgcn_global_load_lds( \
    (const __attribute__((address_space(1))) void*)(const void*)(g), \
    (__attribute__((address_space(3))) void*)(void*)(l), 16, 0, 0)

// ---------- fp32 -> bf16 convert (vectorized) ----------
__global__ void cvt_f32_bf16(const float* __restrict__ in, unsigned short* __restrict__ out, int n4){
  int i = blockIdx.x*256 + threadIdx.x;
  if (i < n4){
    float4 v = ((const float4*)in)[i];
    us4v o = { f2bf(v.x), f2bf(v.y), f2bf(v.z), f2bf(v.w) };
    ((us4v*)out)[i] = o;
  }
}

// ---------- weight transpose + convert: W[K][N] f32 -> WT[Npad][K] bf16 ----------
__global__ void wtrans(const float* __restrict__ W, unsigned short* __restrict__ WT,
                       int K, int N){
  __shared__ float t[32][33];
  int n0 = blockIdx.x*32, k0 = blockIdx.y*32;
  int tx = threadIdx.x & 31, ty = threadIdx.x >> 5;
  #pragma unroll
  for (int i = ty; i < 32; i += 8){
    int k = k0 + i, n = n0 + tx;
    t[i][tx] = (n < N) ? W[(size_t)k*N + n] : 0.f;
  }
  __syncthreads();
  #pragma unroll
  for (int i = ty; i < 32; i += 8){
    int n = n0 + i, k = k0 + tx;
    WT[(size_t)n*K + k] = f2bf(t[tx][i]);
  }
}

// ---------- bf16 GEMM core: C[M][N] = A[M][K] @ BT[N][K]^T + bias ----------
// 128x128 tile, BK=64, 4 waves, 16x16x32 MFMA, global_load_lds staging.
// LDS rows are 128B -> XOR-chunk swizzle (chunk c ^= row&7) on global source
// (linear LDS dest) + on ds_read address.
template<bool OUTF32>
__device__ __forceinline__ void gemm_core(
  unsigned short* As, unsigned short* Bs,
  const unsigned short* __restrict__ A, int lda,
  const unsigned short* __restrict__ BT,
  const float* __restrict__ bias,
  void* __restrict__ Cv, int ldc,
  int N, int K, int bx, int by)
{
  const int tid = threadIdx.x;
  const int wave = tid>>6, lane = tid&63, lq = lane&15, lg = lane>>4;
  const int tm = by*128, tn = bx*128;
  const int wm = (wave>>1)*64, wn = (wave&1)*64;
  f32x4 acc[4][4] = {};
  char* AsB = (char*)As; char* BsB = (char*)Bs;
  const int r8 = tid>>3;                 // row within 32-row group
  const int sc = ((tid&7) ^ (r8&7))*8;   // swizzled source col (shorts)
  for (int kt = 0; kt < K; kt += 64){
    __syncthreads();
    #pragma unroll
    for (int rd=0; rd<4; rd++){
      GLOAD16(A  + (size_t)(tm + rd*32 + r8)*lda + kt + sc, AsB + rd*4096 + wave*1024);
      GLOAD16(BT + (size_t)(tn + rd*32 + r8)*K   + kt + sc, BsB + rd*4096 + wave*1024);
    }
    asm volatile("s_waitcnt vmcnt(0)" ::: "memory");
    __syncthreads();
    #pragma unroll
    for (int h=0; h<2; h++){
      bf16x8 af[4], bfr[4];
      #pragma unroll
      for (int i=0;i<4;i++) af[i]  = *(const bf16x8*)(AsB + (wm+16*i+lq)*128 + ((((h*4+lg)^(lq&7)))<<4));
      #pragma unroll
      for (int j=0;j<4;j++) bfr[j] = *(const bf16x8*)(BsB + (wn+16*j+lq)*128 + ((((h*4+lg)^(lq&7)))<<4));
      #pragma unroll
      for (int i=0;i<4;i++)
        #pragma unroll
        for (int j=0;j<4;j++)
          acc[i][j] = __builtin_amdgcn_mfma_f32_16x16x32_bf16(af[i], bfr[j], acc[i][j], 0,0,0);
    }
  }
  #pragma unroll
  for (int i=0;i<4;i++){
    #pragma unroll
    for (int j=0;j<4;j++){
      int col = tn + wn + 16*j + lq;
      if (col < N){
        float bv = bias ? bias[col] : 0.f;
        #pragma unroll
        for (int r=0;r<4;r++){
          int row = tm + wm + 16*i + lg*4 + r;
          float v = acc[i][j][r] + bv;
          if (OUTF32) ((float*)Cv)[(size_t)row*ldc + col] = v;
          else ((unsigned short*)Cv)[(size_t)row*ldc + col] = f2bf(v);
        }
      }
    }
  }
}

// XCD-chunked bijective remap (requires nwg % 8 == 0 — all our grids comply):
// consecutive remapped blocks within one XCD sweep bx fast -> A-panel (by)
// stays resident in that XCD's L2.
__device__ __forceinline__ void xcd_remap(int& bx, int& by){
  int nwg = gridDim.x*gridDim.y;
  int lin = blockIdx.y*gridDim.x + blockIdx.x;
  int wg = (lin&7)*(nwg>>3) + (lin>>3);
  bx = wg % gridDim.x; by = wg / gridDim.x;
}

template<bool OUTF32>
__global__ __launch_bounds__(256) void gemm_bt(
  const unsigned short* __restrict__ A, int lda,
  const unsigned short* __restrict__ BT,
  const float* __restrict__ bias,
  void* __restrict__ Cv, int ldc, int N, int K)
{
  __shared__ unsigned short As[128*64];
  __shared__ unsigned short Bs[128*64];
  int bx, by; xcd_remap(bx, by);
  gemm_core<OUTF32>(As, Bs, A, lda, BT, bias, Cv, ldc, N, K, bx, by);
}

// two independent GEMMs in one dispatch (better CU fill, fewer tails)
__global__ __launch_bounds__(256) void gemm_bt_dual(
  const unsigned short* __restrict__ A0, int lda0, const unsigned short* __restrict__ BT0,
  const float* __restrict__ b0, void* __restrict__ C0, int ldc0, int N0, int K0,
  const unsigned short* __restrict__ A1, int lda1, const unsigned short* __restrict__ BT1,
  const float* __restrict__ b1, void* __restrict__ C1, int ldc1, int N1, int K1,
  int split)
{
  __shared__ unsigned short As[128*64];
  __shared__ unsigned short Bs[128*64];
  int bx, by; xcd_remap(bx, by);
  if (bx < split)
    gemm_core<false>(As, Bs, A0, lda0, BT0, b0, C0, ldc0, N0, K0, bx, by);
  else
    gemm_core<false>(As, Bs, A1, lda1, BT1, b1, C1, ldc1, N1, K1, bx - split, by);
}

// ---------- fused: rmsnorm(cq), rmsnorm(ckv), rope_k ----------
__device__ __forceinline__ void rms_row(unsigned short* x, int D, float* red){
  int tid = threadIdx.x;
  float ss = 0.f;
  for (int i = tid; i < D; i += 256){ float v = bf2f(x[i]); ss += v*v; }
  #pragma unroll
  for (int o=32;o;o>>=1) ss += __shfl_xor(ss, o, 64);
  if ((tid&63)==0) red[tid>>6] = ss;
  __syncthreads();
  float tot = red[0]+red[1]+red[2]+red[3];
  float sc = rsqrtf(tot/(float)D + 1e-6f);
  for (int i = tid; i < D; i += 256) x[i] = f2bf(bf2f(x[i])*sc);
}

__global__ void norms_fused(unsigned short* __restrict__ cq,
                            unsigned short* __restrict__ ckv,
                            unsigned short* __restrict__ kr){
  __shared__ float red[4];
  int bid = blockIdx.x;
  if (bid < NTOK){
    rms_row(cq + (size_t)bid*QLR, QLR, red);
  } else if (bid < 2*NTOK){
    rms_row(ckv + (size_t)(bid-NTOK)*CKVD + DR, KVLR, red);
  } else {
    // rope_k: 512 blocks x 256 threads over NTOK*32
    int idx = (bid - 2*NTOK)*256 + threadIdx.x;
    int j = idx & 31;
    int t = idx >> 5;
    int s = t & (SS-1);
    const unsigned short* src = ckv + (size_t)t*CKVD;
    float xr = bf2f(src[j]), xi = bf2f(src[j+32]);
    float freq = powf(10000.f, -(float)(2*j)/64.f);
    float ang = (float)s * freq;
    float c = cosf(ang), sn = sinf(ang);
    kr[(size_t)t*64 + j]      = f2bf(xr*c - xi*sn);
    kr[(size_t)t*64 + j + 32] = f2bf(xi*c + xr*sn);
  }
}

// ---------- fused: rope_q (in-place) + V transpose ----------
__global__ void ropeq_vt_fused(unsigned short* __restrict__ q,
                               const unsigned short* __restrict__ kv,
                               unsigned short* __restrict__ vT){
  int bid = blockIdx.x;
  if (bid < NTOK*NH*32/256){
    int idx = bid*256 + threadIdx.x;   // B*S*H*32
    int j = idx & 31;
    int h = (idx >> 5) & 15;
    int t = idx >> 9;            // token
    int s = t & (SS-1);
    unsigned short* base = q + (size_t)t*QD + h*(DN+DR) + DN;
    float xr = bf2f(base[j]), xi = bf2f(base[j+32]);
    float freq = powf(10000.f, -(float)(2*j)/64.f);
    float ang = (float)s * freq;
    float c = cosf(ang), sn = sinf(ang);
    base[j]    = f2bf(xr*c - xi*sn);
    base[j+32] = f2bf(xi*c + xr*sn);
  } else {
    __shared__ unsigned short t[32][33];
    int idx = bid - NTOK*NH*32/256;    // 8192 tiles: (s0i 64, d0i 4, bh 32)
    int s0 = (idx & 63)*32, d0 = ((idx>>6)&3)*32, bh = idx>>8;
    int b = bh>>4, h = bh&15;
    int tx = threadIdx.x & 31, ty = threadIdx.x >> 5;
    #pragma unroll
    for (int i = ty; i < 32; i += 8)
      t[i][tx] = kv[((size_t)(b*SS + s0+i))*KVD + h*(DN+DV) + DN + d0 + tx];
    __syncthreads();
    #pragma unroll
    for (int i = ty; i < 32; i += 8)
      vT[((size_t)(bh*DV + d0+i))*SS + s0 + tx] = t[tx][i];
  }
}

// ---------- causal flash attention ----------
// 1024 blocks, one 64-row q-tile each. XCD decode keeps all qt-blocks of a
// bh on one XCD (lin%8 == bh%8); qt = 31-(lin>>5) launches big tiles first
// (greedy balance). 2 LDS buffers (44 KB) -> 3 blocks/CU co-resident: TLP
// hides the QK^T->softmax->PV dependency chain (round-4: nothing saturated
// at 2 blocks/CU). 1-deep prefetch: loads are L2-resident (~300cy), fully
// covered by the compute phase, so vmcnt(0) after compute is ~free.
__global__ __launch_bounds__(256) void attn_kernel(
  const unsigned short* __restrict__ q,   // [NTOK][3072] rope-applied
  const unsigned short* __restrict__ kv,  // [NTOK][4096]
  const unsigned short* __restrict__ kr,  // [NTOK][64] roped
  const unsigned short* __restrict__ vT,  // [32][128][S]
  unsigned short* __restrict__ attn)      // [NTOK][2048]
{
  __shared__ unsigned short Ksn[2][32*128];
  __shared__ unsigned short Ksr[2][32*64];
  __shared__ unsigned short Vs [2][128*32];
  __shared__ unsigned short Ps [4*512];
  const int tid = threadIdx.x, wave = tid>>6, lane = tid&63, lq = lane&15, lg = lane>>4;
  const int lin = blockIdx.x;
  const int bh = (lin&7) + 8*((lin>>3)&3);
  const int qt = NQT-1 - (lin>>5);
  const int b = bh>>4, h = bh&15;
  const float kmul = 1.44269504f * 0.07216878364f; // log2e / sqrt(192)

  // per-thread staging pointers (advance per k-step)
  const int rK = tid>>4, cK = (tid&15) ^ ((tid>>4)&7);
  const int rR = tid>>3, cR = (tid&7) ^ ((tid>>3)&7);
  const unsigned short* pKn0 = kv + (size_t)(b*SS + rK)*KVD + h*(DN+DV) + cK*8;
  const unsigned short* pKn1 = pKn0 + (size_t)16*KVD;
  const unsigned short* pKr  = kr + (size_t)(b*SS + rR)*64 + cR*8;
  const unsigned short* pV0  = vT + ((size_t)bh*DV + (tid>>2))*SS + (tid&3)*8;
  const unsigned short* pV1  = pV0 + (size_t)64*SS;

#define STAGE_ATTN(bufi) do {                                                 \
    GLOAD16(pKn0, (char*)Ksn[bufi] +        wave*1024);                       \
    GLOAD16(pKn1, (char*)Ksn[bufi] + 4096 + wave*1024);                       \
    GLOAD16(pKr,  (char*)Ksr[bufi] +        wave*1024);                       \
    GLOAD16(pV0,  (char*)Vs[bufi]  +        wave*1024);                       \
    GLOAD16(pV1,  (char*)Vs[bufi]  + 4096 + wave*1024);                       \
    pKn0 += 32*KVD; pKn1 += 32*KVD; pKr += 32*64; pV0 += 32; pV1 += 32;       \
  } while(0)

  const int qw = qt*64 + wave*16;
  const int myq = qw + lq;
  bf16x8 qf[6];
  {
    const unsigned short* qrow = q + (size_t)(b*SS + qw + lq)*QD + h*(DN+DR);
    #pragma unroll
    for (int ks=0;ks<6;ks++) qf[ks] = *(const bf16x8*)(qrow + ks*32 + lg*8);
  }
  f32x4 oacc[8] = {};
  float m = -1e30f, lsum = 0.f;
  const int nkt = 2*qt + 2;

  STAGE_ATTN(0);
  asm volatile("s_waitcnt vmcnt(0)" ::: "memory");
  __builtin_amdgcn_s_barrier();
  int cur = 0;
  for (int kt = 0; kt < nkt; kt++){
    if (kt+1 < nkt) STAGE_ATTN(cur^1);
    // ---- QK^T (swizzled K reads) ----
    f32x4 sacc[2] = {};
    __builtin_amdgcn_s_setprio(1);
    #pragma unroll
    for (int jf=0;jf<2;jf++){
      const int rowb = jf*16 + lq;
      #pragma unroll
      for (int ks=0;ks<4;ks++){
        bf16x8 kf = *(const bf16x8*)((char*)Ksn[cur] + rowb*256 + ((((ks*4+lg)^(lq&7)))<<4));
        sacc[jf] = __builtin_amdgcn_mfma_f32_16x16x32_bf16(kf, qf[ks], sacc[jf], 0,0,0);
      }
      #pragma unroll
      for (int ks=0;ks<2;ks++){
        bf16x8 kf = *(const bf16x8*)((char*)Ksr[cur] + rowb*128 + ((((ks*4+lg)^(lq&7)))<<4));
        sacc[jf] = __builtin_amdgcn_mfma_f32_16x16x32_bf16(kf, qf[4+ks], sacc[jf], 0,0,0);
      }
    }
    __builtin_amdgcn_s_setprio(0);
    // ---- online softmax (q lane-local: col=lq) ----
    float sv[2][4]; float pmax = -1e30f;
    if (kt*32 + 31 <= qw){          // wave-uniform: fully visible tile
      #pragma unroll
      for (int jf=0;jf<2;jf++)
        #pragma unroll
        for (int r=0;r<4;r++){ float s = sacc[jf][r]*kmul; sv[jf][r]=s; pmax=fmaxf(pmax,s); }
    } else {
      #pragma unroll
      for (int jf=0;jf<2;jf++)
        #pragma unroll
        for (int r=0;r<4;r++){
          int kpos = kt*32 + jf*16 + lg*4 + r;
          float s = (kpos <= myq) ? sacc[jf][r]*kmul : -1e30f;
          sv[jf][r]=s; pmax=fmaxf(pmax,s);
        }
    }
    pmax = fmaxf(pmax, __shfl_xor(pmax, 16, 64));
    pmax = fmaxf(pmax, __shfl_xor(pmax, 32, 64));
    if (!__all(pmax <= m + 8.f)){   // defer-max: rescale only on real growth
      float mnew = fmaxf(m, pmax);
      float alpha = __builtin_amdgcn_exp2f(m - mnew);
      m = mnew;
      lsum *= alpha;
      #pragma unroll
      for (int df=0;df<8;df++)
        #pragma unroll
        for (int r=0;r<4;r++) oacc[df][r] *= alpha;
    }
    float psum = 0.f;
    #pragma unroll
    for (int jf=0;jf<2;jf++){
      float p0 = __builtin_amdgcn_exp2f(sv[jf][0] - m);
      float p1 = __builtin_amdgcn_exp2f(sv[jf][1] - m);
      float p2 = __builtin_amdgcn_exp2f(sv[jf][2] - m);
      float p3 = __builtin_amdgcn_exp2f(sv[jf][3] - m);
      psum += (p0+p1)+(p2+p3);
      uint2 pk = { cvt_pk_bf16(p0,p1), cvt_pk_bf16(p2,p3) };
      *(uint2*)((char*)Ps + wave*1024 + lq*64 + jf*32 + lg*8) = pk;
    }
    psum += __shfl_xor(psum, 16, 64);
    psum += __shfl_xor(psum, 32, 64);
    lsum += psum;
    bf16x8 pf = *(const bf16x8*)((char*)Ps + wave*1024 + lq*64 + lg*16);
    // ---- PV ----
    __builtin_amdgcn_s_setprio(1);
    #pragma unroll
    for (int df=0;df<8;df++){
      bf16x8 vf = *(const bf16x8*)(Vs[cur] + (df*16+lq)*32 + lg*8);
      oacc[df] = __builtin_amdgcn_mfma_f32_16x16x32_bf16(vf, pf, oacc[df], 0,0,0);
    }
    __builtin_amdgcn_s_setprio(0);
    asm volatile("s_waitcnt vmcnt(0)" ::: "memory");
    __builtin_amdgcn_s_barrier();
    cur ^= 1;
  }
  float inv = 1.f / lsum;
  #pragma unroll
  for (int df=0;df<8;df++){
    uint2 o = { cvt_pk_bf16(oacc[df][0]*inv, oacc[df][1]*inv),
                cvt_pk_bf16(oacc[df][2]*inv, oacc[df][3]*inv) };
    *(uint2*)(attn + (size_t)(b*SS + myq)*2048 + h*DV + df*16 + lg*4) = o;
  }
#undef STAGE_ATTN
}

// ---------- launch ----------
extern "C" void kernel_launch(void* const* d_in, const int* in_sizes, int n_in,
                              void* d_out, int out_size, void* d_ws, size_t ws_size,
                              hipStream_t stream){
  const float* X    = (const float*)d_in[0];
  const float* Wqd  = (const float*)d_in[2];
  const float* bqd  = (const float*)d_in[3];
  const float* Wqu  = (const float*)d_in[4];
  const float* bqu  = (const float*)d_in[5];
  const float* Wkvd = (const float*)d_in[6];
  const float* bkvd = (const float*)d_in[7];
  const float* Wkvu = (const float*)d_in[8];
  const float* bkvu = (const float*)d_in[9];
  const float* Wo   = (const float*)d_in[10];
  const float* bo   = (const float*)d_in[11];
  float* out = (float*)d_out;

  char* ws = (char*)d_ws;
  // workspace layout (bytes); attn output overlays Xb (dead after G1G3)
  unsigned short* Xb    = (unsigned short*)(ws + 0);          // 16,777,216
  unsigned short* attnb = (unsigned short*)(ws + 0);
  char*           arena = ws + 16777216;                      // 14,680,064 (weight arena)
  unsigned short* Wt1 = (unsigned short*)(arena);             // 1536x2048x2 = 6,291,456
  unsigned short* Wt3 = (unsigned short*)(arena + 6291456);   // 640x2048x2  = 2,621,440
  unsigned short* Wt2 = (unsigned short*)(arena);             // 3072x1536x2 = 9,437,184
  unsigned short* Wt4 = (unsigned short*)(arena + 9437184);   // 4096x512x2  = 4,194,304
  unsigned short* Wt5 = (unsigned short*)(arena);             // 2048x2048x2 = 8,388,608
  unsigned short* cq   = (unsigned short*)(ws + 31457280);    // 12,582,912
  unsigned short* qtmp = (unsigned short*)(ws + 44040192);    // 25,165,824
  unsigned short* ckv  = (unsigned short*)(ws + 69206016);    //  4,718,592
  unsigned short* kvt  = (unsigned short*)(ws + 73924608);    // 33,554,432
  unsigned short* kr   = (unsigned short*)(ws + 107479040);   //    524,288
  unsigned short* vT   = (unsigned short*)(ws + 108003328);   // 16,777,216  (end 124,780,544)

  // 1. X -> bf16
  cvt_f32_bf16<<<dim3(NTOK*HID/4/256), 256, 0, stream>>>(X, Xb, NTOK*HID/4);
  // 2. W transposes for down-projections, fused G1+G3
  wtrans<<<dim3(QLR/32, HID/32), 256, 0, stream>>>(Wqd, Wt1, HID, QLR);
  wtrans<<<dim3(640/32, HID/32), 256, 0, stream>>>(Wkvd, Wt3, HID, CKVD);
  gemm_bt_dual<<<dim3(QLR/128 + 640/128, NTOK/128), 256, 0, stream>>>(
      Xb, HID, Wt1, bqd, cq, QLR, QLR, HID,
      Xb, HID, Wt3, bkvd, ckv, CKVD, CKVD, HID, QLR/128);
  // 3. norms + k rope (fused)
  norms_fused<<<dim3(2*NTOK + NTOK*32/256), 256, 0, stream>>>(cq, ckv, kr);
  // 4. W transposes for up-projections, fused G2+G4
  wtrans<<<dim3(QD/32, QLR/32), 256, 0, stream>>>(Wqu, Wt2, QLR, QD);
  wtrans<<<dim3(KVD/32, KVLR/32), 256, 0, stream>>>(Wkvu, Wt4, KVLR, KVD);
  gemm_bt_dual<<<dim3(QD/128 + KVD/128, NTOK/128), 256, 0, stream>>>(
      cq, QLR, Wt2, bqu, qtmp, QD, QD, QLR,
      ckv + DR, CKVD, Wt4, bkvu, kvt, KVD, KVD, KVLR, QD/128);
  // 5. q rope + V^T (fused)
  ropeq_vt_fused<<<dim3(NTOK*NH*32/256 + 8192), 256, 0, stream>>>(qtmp, kvt, vT);
  // 6. attention (1024 one-tile blocks, XCD-grouped, big-qt first)
  attn_kernel<<<dim3(NQT * BB*NH), 256, 0, stream>>>(qtmp, kvt, kr, vT, attnb);
  // 7. Wo^T ; GEMM5 -> out (f32)
  wtrans<<<dim3(HID/32, HID/32), 256, 0, stream>>>(Wo, Wt5, HID, HID);
  gemm_bt<true><<<dim3(HID/128, NTOK/128), 256, 0, stream>>>(attnb, HID, Wt5, bo, out, HID, HID, HID);
}